// Round 9
// baseline (426.327 us; speedup 1.0000x reference)
//
#include <hip/hip_runtime.h>
#include <math.h>

constexpr int Bn  = 32;
constexpr int Tn  = 1024;
constexpr int INn = 32;
constexpr int En  = 256;
constexpr int Pn  = 32;

typedef short bf16x8 __attribute__((ext_vector_type(8)));
typedef float f32x4  __attribute__((ext_vector_type(4)));

__device__ __forceinline__ unsigned short f2bf(float f) {
    unsigned int b = __float_as_uint(f);
    b += 0x7FFF + ((b >> 16) & 1);          // RNE
    return (unsigned short)(b >> 16);
}
__device__ __forceinline__ float bf2f(unsigned short h) {
    return __uint_as_float(((unsigned int)h) << 16);
}
// pack trunc-bf16(lo), trunc-bf16(hi) in ONE v_perm (bytes [2,3] of each)
__device__ __forceinline__ unsigned int permpack(float lo, float hi) {
    return __builtin_amdgcn_perm(__float_as_uint(hi), __float_as_uint(lo),
                                 0x07060302u);
}

// ---------- K0: prep (only what k_qkv needs) ----------
// [0,96): Wcb bf16 = in_proj_w @ ip_w  |  [96,99): bc
__global__ __launch_bounds__(256) void k_prep(const float* __restrict__ ipw,
                                              const float* __restrict__ ipb,
                                              const float* __restrict__ inw,
                                              const float* __restrict__ inb,
                                              unsigned short* __restrict__ Wcb,
                                              float* __restrict__ bc) {
    int blk = blockIdx.x, tid = threadIdx.x;
    if (blk < 96) {
        int idx = blk * 256 + tid;
        int o = idx >> 5, i = idx & 31;
        const float* wr = inw + (size_t)o * En;
        float a0 = 0.f, a1 = 0.f;
        for (int e = 0; e < En; e += 2) {
            a0 += wr[e]     * ipw[(size_t)e * INn + i];
            a1 += wr[e + 1] * ipw[(size_t)(e + 1) * INn + i];
        }
        Wcb[(size_t)o * INn + i] = f2bf(a0 + a1);
    } else {
        int o = (blk - 96) * 256 + tid;
        const float* wr = inw + (size_t)o * En;
        float a = inb[o];
        for (int e = 0; e < En; ++e) a += wr[e] * ipb[e];
        bc[o] = a;
    }
}

// ---------- K1: qkv projection (blocks 0..511) + weight conversions ----------
// [512,576): Wb=bf16(out_w) | [576,608): w1 hi/lo | [608,864): prw hi/lo
__global__ __launch_bounds__(256, 2) void k_qkv(const float* __restrict__ x,
                                                const unsigned short* __restrict__ Wcb,
                                                const float* __restrict__ bc,
                                                const float* __restrict__ outw,
                                                const float* __restrict__ w1,
                                                const float* __restrict__ prw,
                                                unsigned short* __restrict__ Qb,
                                                unsigned short* __restrict__ Kb,
                                                unsigned short* __restrict__ Vt,
                                                unsigned short* __restrict__ Wb,
                                                unsigned short* __restrict__ w1h,
                                                unsigned short* __restrict__ w1l,
                                                unsigned short* __restrict__ pwh,
                                                unsigned short* __restrict__ pwl) {
    int tid = threadIdx.x;
    if (blockIdx.x >= 512) {
        int cb = blockIdx.x - 512;
        if (cb < 64) {
            int idx = cb * 256 + tid;              // 16384 float4s
            float4 a = *(const float4*)(outw + (size_t)idx * 4);
            unsigned int u0 = f2bf(a.x) | ((unsigned int)f2bf(a.y) << 16);
            unsigned int u1 = f2bf(a.z) | ((unsigned int)f2bf(a.w) << 16);
            *(uint2*)(Wb + (size_t)idx * 4) = make_uint2(u0, u1);
        } else if (cb < 96) {
            int idx = (cb - 64) * 256 + tid;       // 8192 elements
            float a = w1[idx];
            unsigned short h = f2bf(a);
            w1h[idx] = h;
            w1l[idx] = f2bf(a - bf2f(h));
        } else {
            int idx = (cb - 96) * 256 + tid;       // 65536 elements
            float a = prw[idx];
            unsigned short h = f2bf(a);
            pwh[idx] = h;
            pwl[idx] = f2bf(a - bf2f(h));
        }
        return;
    }
    int wv = tid >> 6, lane = tid & 63;
    int cl = lane & 15, quad = lane >> 4;
    int m0 = blockIdx.x * 64;
    int b = m0 >> 10, tl0 = m0 & 1023;
    int n0w = wv * 192;
    f32x4 zero4 = {0.f, 0.f, 0.f, 0.f};

    bf16x8 wfrag[12]; float bv[12];
#pragma unroll
    for (int nt = 0; nt < 12; ++nt) {
        int col = n0w + nt * 16 + cl;
        wfrag[nt] = *(const bf16x8*)(Wcb + (size_t)col * 32 + quad * 8);
        bv[nt] = bc[col];
    }
#pragma unroll
    for (int mt = 0; mt < 4; ++mt) {
        const float* xr = x + (size_t)(m0 + mt * 16 + cl) * 32 + quad * 8;
        float4 xa = *(const float4*)xr, xc = *(const float4*)(xr + 4);
        bf16x8 af;
        af[0] = (short)f2bf(xa.x); af[1] = (short)f2bf(xa.y);
        af[2] = (short)f2bf(xa.z); af[3] = (short)f2bf(xa.w);
        af[4] = (short)f2bf(xc.x); af[5] = (short)f2bf(xc.y);
        af[6] = (short)f2bf(xc.z); af[7] = (short)f2bf(xc.w);
        f32x4 acc[12];
#pragma unroll
        for (int nt = 0; nt < 12; ++nt)
            acc[nt] = __builtin_amdgcn_mfma_f32_16x16x32_bf16(af, wfrag[nt], zero4, 0, 0, 0);
        int tloc = tl0 + mt * 16 + quad * 4;
#pragma unroll
        for (int nt = 0; nt < 12; ++nt) {
            int col = n0w + nt * 16 + cl;
            int slot = col >> 8, c = col & 255;
            int h = c >> 6, d = c & 63;
            int bh = b * 4 + h;
            if (slot == 2) {
                unsigned int u0 = f2bf(acc[nt][0] + bv[nt]) |
                                  ((unsigned int)f2bf(acc[nt][1] + bv[nt]) << 16);
                unsigned int u1 = f2bf(acc[nt][2] + bv[nt]) |
                                  ((unsigned int)f2bf(acc[nt][3] + bv[nt]) << 16);
                *(uint2*)(Vt + ((size_t)bh * 64 + d) * 1024 + tloc) = make_uint2(u0, u1);
            } else {
                unsigned short* dst = (slot ? Kb : Qb) +
                                      ((size_t)bh * 1024 + tloc) * 64 + d;
#pragma unroll
                for (int r = 0; r < 4; ++r)
                    dst[(size_t)r * 64] = f2bf(acc[nt][r] + bv[nt]);
            }
        }
    }
}

// ---------- K2: MFMA flash attention, 64 q/wave + block K-split ----------
// grid 1024: bh = blk&127, qb = (blk>>7)&3, half = blk>>9.
// 4 blocks/CU (LDS 38.9KB), 16 waves/CU; K/V LDS reads amortized over 4 tt.
__global__ __launch_bounds__(256, 4) void k_attn(const unsigned short* __restrict__ Qb,
                                                 const unsigned short* __restrict__ Kb,
                                                 const unsigned short* __restrict__ Vt,
                                                 unsigned short* __restrict__ Po0,
                                                 unsigned short* __restrict__ Po1,
                                                 float* __restrict__ L0,
                                                 float* __restrict__ L1) {
    __shared__ unsigned short Ks[64][72];
    __shared__ unsigned short Vs[64][72];
    __shared__ __align__(16) unsigned short Pl[4][4][16][40];
    int blk = blockIdx.x;
    int bh = blk & 127;
    int r_ = blk >> 7;
    int qb = r_ & 3, half = r_ >> 2;
    int b = bh >> 2, h = bh & 3;
    int tid = threadIdx.x;
    int wv = tid >> 6, lane = tid & 63;
    int cl = lane & 15, quad = lane >> 4;
    int qbase = qb * 256 + wv * 64;
    const float SCL = 0.18033688f;                 // 0.125 * log2(e)

    f32x4 zero4 = {0.f, 0.f, 0.f, 0.f};
    bf16x8 qfrag[4][2];
#pragma unroll
    for (int tt = 0; tt < 4; ++tt)
#pragma unroll
        for (int ch = 0; ch < 2; ++ch)
            qfrag[tt][ch] = *(const bf16x8*)(Qb +
                ((size_t)bh * 1024 + qbase + tt * 16 + cl) * 64 + ch * 32 + quad * 8);
    f32x4 acc[4][4];
#pragma unroll
    for (int tt = 0; tt < 4; ++tt)
#pragma unroll
        for (int dt = 0; dt < 4; ++dt) acc[tt][dt] = zero4;
    float l[4] = {0.f, 0.f, 0.f, 0.f};

    const unsigned short* Kbase = Kb + (size_t)bh * 65536;
    const unsigned short* Vbase = Vt + (size_t)bh * 65536;

    for (int kt = 0; kt < 8; ++kt) {
        int ktt = half * 8 + kt;
#pragma unroll
        for (int r = 0; r < 2; ++r) {
            int idx = r * 256 + tid; int row = idx >> 3, c16 = idx & 7;
            *(uint4*)&Ks[row][c16 * 8] =
                *(const uint4*)(Kbase + (size_t)(ktt * 64 + row) * 64 + c16 * 8);
            *(uint4*)&Vs[row][c16 * 8] =
                *(const uint4*)(Vbase + (size_t)row * 1024 + ktt * 64 + c16 * 8);
        }
        __syncthreads();
#pragma unroll
        for (int c = 0; c < 2; ++c) {
            bf16x8 ka0 = *(const bf16x8*)&Ks[c * 32 + cl][quad * 8];
            bf16x8 ka1 = *(const bf16x8*)&Ks[c * 32 + cl][32 + quad * 8];
            bf16x8 kb0 = *(const bf16x8*)&Ks[c * 32 + 16 + cl][quad * 8];
            bf16x8 kb1 = *(const bf16x8*)&Ks[c * 32 + 16 + cl][32 + quad * 8];
            bf16x8 va[4];
#pragma unroll
            for (int dt = 0; dt < 4; ++dt)
                va[dt] = *(const bf16x8*)&Vs[dt * 16 + cl][c * 32 + quad * 8];
#pragma unroll
            for (int tt = 0; tt < 4; ++tt) {
                f32x4 s0 = __builtin_amdgcn_mfma_f32_16x16x32_bf16(ka0, qfrag[tt][0], zero4, 0, 0, 0);
                s0 = __builtin_amdgcn_mfma_f32_16x16x32_bf16(ka1, qfrag[tt][1], s0, 0, 0, 0);
                f32x4 s1 = __builtin_amdgcn_mfma_f32_16x16x32_bf16(kb0, qfrag[tt][0], zero4, 0, 0, 0);
                s1 = __builtin_amdgcn_mfma_f32_16x16x32_bf16(kb1, qfrag[tt][1], s1, 0, 0, 0);
                float p0 = exp2f(SCL * s0[0]), p1 = exp2f(SCL * s0[1]);
                float p2 = exp2f(SCL * s0[2]), p3 = exp2f(SCL * s0[3]);
                float p4 = exp2f(SCL * s1[0]), p5 = exp2f(SCL * s1[1]);
                float p6 = exp2f(SCL * s1[2]), p7 = exp2f(SCL * s1[3]);
                unsigned int w0 = permpack(p0, p1);
                unsigned int w1 = permpack(p2, p3);
                unsigned int w2 = permpack(p4, p5);
                unsigned int w3 = permpack(p6, p7);
                // l from the SAME truncated values -> bias cancels in o/l
                l[tt] += ((__uint_as_float(w0 << 16) + __uint_as_float(w0 & 0xffff0000u)) +
                          (__uint_as_float(w1 << 16) + __uint_as_float(w1 & 0xffff0000u))) +
                         ((__uint_as_float(w2 << 16) + __uint_as_float(w2 & 0xffff0000u)) +
                          (__uint_as_float(w3 << 16) + __uint_as_float(w3 & 0xffff0000u)));
                *(uint2*)&Pl[wv][tt][cl][quad * 4]      = make_uint2(w0, w1);
                *(uint2*)&Pl[wv][tt][cl][16 + quad * 4] = make_uint2(w2, w3);
            }
            asm volatile("s_waitcnt lgkmcnt(0)" ::: "memory");
#pragma unroll
            for (int tt = 0; tt < 4; ++tt) {
                bf16x8 pf = *(const bf16x8*)&Pl[wv][tt][cl][quad * 8];
#pragma unroll
                for (int dt = 0; dt < 4; ++dt)
                    acc[tt][dt] = __builtin_amdgcn_mfma_f32_16x16x32_bf16(pf, va[dt], acc[tt][dt], 0, 0, 0);
            }
        }
        __syncthreads();
    }
    // epilogue: raw partial o (bf16) + partial l (fp32)
#pragma unroll
    for (int tt = 0; tt < 4; ++tt) {
        l[tt] += __shfl_xor(l[tt], 16);
        l[tt] += __shfl_xor(l[tt], 32);
    }
    unsigned short* Po = half ? Po1 : Po0;
    float* Lp = half ? L1 : L0;
#pragma unroll
    for (int tt = 0; tt < 4; ++tt) {
#pragma unroll
        for (int r = 0; r < 4; ++r) {
            size_t row = (size_t)(b * 1024 + qbase + tt * 16 + quad * 4 + r) * En;
#pragma unroll
            for (int dt = 0; dt < 4; ++dt)
                Po[row + h * 64 + dt * 16 + cl] = f2bf(acc[tt][dt][r]);
        }
    }
    if (quad == 0) {
#pragma unroll
        for (int tt = 0; tt < 4; ++tt)
            Lp[bh * 1024 + qbase + tt * 16 + cl] = l[tt];
    }
}

// ---------- K3: combine halves + attn_out = ctx @ out_w^T + out_b ----------
__global__ __launch_bounds__(256) void k_out(const unsigned short* __restrict__ Po0,
                                             const unsigned short* __restrict__ Po1,
                                             const float* __restrict__ L0,
                                             const float* __restrict__ L1,
                                             const unsigned short* __restrict__ Wb,
                                             const float* __restrict__ bias,
                                             float* __restrict__ AO) {
    __shared__ unsigned short As[64][32];
    __shared__ unsigned short Bs[256][32];
    int tid = threadIdx.x;
    int wv = tid >> 6, lane = tid & 63;
    int cl = lane & 15, quad = lane >> 4;
    size_t m0 = (size_t)blockIdx.x * 64;

    f32x4 acc[4][4];
#pragma unroll
    for (int mt = 0; mt < 4; ++mt)
#pragma unroll
        for (int nt = 0; nt < 4; ++nt) acc[mt][nt] = {0.f, 0.f, 0.f, 0.f};

    for (int kt = 0; kt < 8; ++kt) {
        if (kt) __syncthreads();
        {
            int row = tid >> 2, c4 = tid & 3;
            size_t g = (m0 + row) * En + kt * 32 + c4 * 8;
            uint4 u0 = *(const uint4*)(Po0 + g);
            uint4 u1 = *(const uint4*)(Po1 + g);
            int gt = (int)(m0 + row);
            int li = ((gt >> 10) * 4 + (kt >> 1)) * 1024 + (gt & 1023);
            float linv = 1.f / (L0[li] + L1[li]);
            unsigned int a0[4] = {u0.x, u0.y, u0.z, u0.w};
            unsigned int a1[4] = {u1.x, u1.y, u1.z, u1.w};
            unsigned int w[4];
#pragma unroll
            for (int j = 0; j < 4; ++j) {
                float lo = (bf2f((unsigned short)(a0[j] & 0xffff)) +
                            bf2f((unsigned short)(a1[j] & 0xffff))) * linv;
                float hi = (bf2f((unsigned short)(a0[j] >> 16)) +
                            bf2f((unsigned short)(a1[j] >> 16))) * linv;
                w[j] = f2bf(lo) | ((unsigned int)f2bf(hi) << 16);
            }
            *(uint4*)&As[row][c4 * 8] = make_uint4(w[0], w[1], w[2], w[3]);
        }
#pragma unroll
        for (int j = 0; j < 4; ++j) {
            int lin = j * 256 + tid; int n = lin >> 2, c = lin & 3;
            *(uint4*)&Bs[n][c * 8] =
                *(const uint4*)(Wb + (size_t)n * En + kt * 32 + c * 8);
        }
        __syncthreads();
        bf16x8 af[4], bfr[4];
#pragma unroll
        for (int mt = 0; mt < 4; ++mt)
            af[mt] = *(const bf16x8*)&As[mt * 16 + cl][quad * 8];
#pragma unroll
        for (int nt = 0; nt < 4; ++nt)
            bfr[nt] = *(const bf16x8*)&Bs[wv * 64 + nt * 16 + cl][quad * 8];
#pragma unroll
        for (int mt = 0; mt < 4; ++mt)
#pragma unroll
            for (int nt = 0; nt < 4; ++nt)
                acc[mt][nt] = __builtin_amdgcn_mfma_f32_16x16x32_bf16(af[mt], bfr[nt], acc[mt][nt], 0, 0, 0);
    }
    float bv[4];
#pragma unroll
    for (int nt = 0; nt < 4; ++nt) bv[nt] = bias[wv * 64 + nt * 16 + cl];
#pragma unroll
    for (int mt = 0; mt < 4; ++mt)
#pragma unroll
        for (int nt = 0; nt < 4; ++nt)
#pragma unroll
            for (int r = 0; r < 4; ++r)
                AO[(m0 + mt * 16 + quad * 4 + r) * En + wv * 64 + nt * 16 + cl] =
                    acc[mt][nt][r] + bv[nt];
}

// ---------- K4: boundary MLP via hi/lo-split bf16 MFMA (~fp32 accurate) ----
__global__ __launch_bounds__(256) void k_bscore(const float* __restrict__ AO,
                                                const unsigned short* __restrict__ w1h,
                                                const unsigned short* __restrict__ w1l,
                                                const float* __restrict__ b1,
                                                const float* __restrict__ w2,
                                                const float* __restrict__ b2,
                                                float* __restrict__ bsc) {
    __shared__ unsigned short Ah[128][72];
    __shared__ unsigned short Al[128][72];
    int tid = threadIdx.x;
    int wv = tid >> 6, lane = tid & 63;
    int cl = lane & 15, quad = lane >> 4;
    int m0 = blockIdx.x * 128;

    f32x4 acc[2][2];
#pragma unroll
    for (int mt = 0; mt < 2; ++mt)
#pragma unroll
        for (int nt = 0; nt < 2; ++nt) acc[mt][nt] = {0.f, 0.f, 0.f, 0.f};

    for (int kt = 0; kt < 4; ++kt) {               // BK = 64
        if (kt) __syncthreads();
#pragma unroll
        for (int j = 0; j < 8; ++j) {
            int lin = j * 256 + tid; int row = lin >> 4, c4 = lin & 15;
            float4 a = *(const float4*)(AO + (size_t)(m0 + row) * En + kt * 64 + c4 * 4);
            unsigned short h0 = f2bf(a.x), h1v = f2bf(a.y), h2 = f2bf(a.z), h3 = f2bf(a.w);
            unsigned short l0 = f2bf(a.x - bf2f(h0)), l1v = f2bf(a.y - bf2f(h1v));
            unsigned short l2 = f2bf(a.z - bf2f(h2)), l3 = f2bf(a.w - bf2f(h3));
            *(uint2*)&Ah[row][c4 * 4] =
                make_uint2(h0 | ((unsigned int)h1v << 16), h2 | ((unsigned int)h3 << 16));
            *(uint2*)&Al[row][c4 * 4] =
                make_uint2(l0 | ((unsigned int)l1v << 16), l2 | ((unsigned int)l3 << 16));
        }
        __syncthreads();
#pragma unroll
        for (int ks = 0; ks < 2; ++ks) {
            bf16x8 bh_[2], bl_[2];
#pragma unroll
            for (int nt = 0; nt < 2; ++nt) {
                size_t off = (size_t)(nt * 16 + cl) * En + kt * 64 + ks * 32 + quad * 8;
                bh_[nt] = *(const bf16x8*)(w1h + off);
                bl_[nt] = *(const bf16x8*)(w1l + off);
            }
#pragma unroll
            for (int mt = 0; mt < 2; ++mt) {
                int row = wv * 32 + mt * 16 + cl;
                bf16x8 ah = *(const bf16x8*)&Ah[row][ks * 32 + quad * 8];
                bf16x8 al = *(const bf16x8*)&Al[row][ks * 32 + quad * 8];
#pragma unroll
                for (int nt = 0; nt < 2; ++nt) {
                    acc[mt][nt] = __builtin_amdgcn_mfma_f32_16x16x32_bf16(ah, bh_[nt], acc[mt][nt], 0, 0, 0);
                    acc[mt][nt] = __builtin_amdgcn_mfma_f32_16x16x32_bf16(ah, bl_[nt], acc[mt][nt], 0, 0, 0);
                    acc[mt][nt] = __builtin_amdgcn_mfma_f32_16x16x32_bf16(al, bh_[nt], acc[mt][nt], 0, 0, 0);
                }
            }
        }
    }
    float b1v[2], w2v[2];
#pragma unroll
    for (int nt = 0; nt < 2; ++nt) {
        b1v[nt] = b1[nt * 16 + cl];
        w2v[nt] = w2[nt * 16 + cl];
    }
    float b2v = b2[0];
#pragma unroll
    for (int mt = 0; mt < 2; ++mt) {
        f32x4 z;
#pragma unroll
        for (int r = 0; r < 4; ++r)
            z[r] = fmaxf(acc[mt][0][r] + b1v[0], 0.f) * w2v[0] +
                   fmaxf(acc[mt][1][r] + b1v[1], 0.f) * w2v[1];
#pragma unroll
        for (int d = 1; d < 16; d <<= 1)
#pragma unroll
            for (int r = 0; r < 4; ++r) z[r] += __shfl_xor(z[r], d);
        if (cl == 0) {
#pragma unroll
            for (int r = 0; r < 4; ++r)
                bsc[m0 + wv * 32 + mt * 16 + quad * 4 + r] =
                    1.f / (1.f + __expf(-(z[r] + b2v)));
        }
    }
}

// ---------- K5: fused tail — scan -> segment-mean -> final linear ----------
// grid 32 (batch), 1024 threads. segs/PE live in LDS only.
__global__ __launch_bounds__(1024) void k_tail(const float* __restrict__ bsc,
                                               const float* __restrict__ AO,
                                               const unsigned short* __restrict__ pwh,
                                               const unsigned short* __restrict__ pwl,
                                               const float* __restrict__ prb,
                                               float* __restrict__ out) {
    __shared__ float s_pre[1024];
    __shared__ float wsum[16];
    __shared__ float s_tot;
    __shared__ int   segs[33];
    __shared__ unsigned short PEh[32][264];
    __shared__ unsigned short PEl[32][264];
    int b = blockIdx.x, t = threadIdx.x;
    // --- phase 1: scan -> segs ---
    float x = bsc[b * Tn + t];
#pragma unroll
    for (int d = 1; d < 64; d <<= 1) {
        float y = __shfl_up(x, d);
        if ((t & 63) >= d) x += y;
    }
    int w = t >> 6;
    if ((t & 63) == 63) wsum[w] = x;
    __syncthreads();
    if (t == 0) {
        float s = 0.f;
        for (int i = 0; i < 16; ++i) { float tmp = wsum[i]; wsum[i] = s; s += tmp; }
        s_tot = s;
    }
    __syncthreads();
    float pre = x + wsum[w];
    s_pre[t] = pre;
    __syncthreads();
    float denom = s_tot + 1e-6f;
    int pid = min((int)floorf(pre / denom * 32.0f), 31);
    int pidprev = -1;
    if (t > 0) pidprev = min((int)floorf(s_pre[t - 1] / denom * 32.0f), 31);
    for (int p = pidprev + 1; p <= pid; ++p) segs[p] = t;
    if (t == 1023)
        for (int p = pid + 1; p <= 32; ++p) segs[p] = Tn;
    __syncthreads();
    // --- phase 2: segment mean -> PE hi/lo (bf16, LDS) ---
    {
        int g = t >> 8, e = t & 255;
#pragma unroll
        for (int i = 0; i < 8; ++i) {
            int p = g * 8 + i;
            int s = segs[p], en = segs[p + 1];
            float sum = 0.f;
            for (int tk = s; tk < en; ++tk)
                sum += AO[((size_t)b * Tn + tk) * En + e];
            float mean = sum / fmaxf((float)(en - s), 1.f);
            unsigned short hh = f2bf(mean);
            PEh[p][e] = hh;
            PEl[p][e] = f2bf(mean - bf2f(hh));
        }
    }
    __syncthreads();
    // --- phase 3: out[b] = PE @ prw^T + prb (hi/lo-split bf16 MFMA) ---
    {
        int wv = t >> 6, lane = t & 63;
        int cl = lane & 15, quad = lane >> 4;
        int n = wv * 16 + cl;
        f32x4 acc[2] = {{0.f, 0.f, 0.f, 0.f}, {0.f, 0.f, 0.f, 0.f}};
        for (int kt = 0; kt < 8; ++kt) {
            bf16x8 bh_ = *(const bf16x8*)(pwh + (size_t)n * En + kt * 32 + quad * 8);
            bf16x8 bl_ = *(const bf16x8*)(pwl + (size_t)n * En + kt * 32 + quad * 8);
#pragma unroll
            for (int mt = 0; mt < 2; ++mt) {
                bf16x8 ah = *(const bf16x8*)&PEh[mt * 16 + cl][kt * 32 + quad * 8];
                bf16x8 al = *(const bf16x8*)&PEl[mt * 16 + cl][kt * 32 + quad * 8];
                acc[mt] = __builtin_amdgcn_mfma_f32_16x16x32_bf16(ah, bh_, acc[mt], 0, 0, 0);
                acc[mt] = __builtin_amdgcn_mfma_f32_16x16x32_bf16(ah, bl_, acc[mt], 0, 0, 0);
                acc[mt] = __builtin_amdgcn_mfma_f32_16x16x32_bf16(al, bh_, acc[mt], 0, 0, 0);
            }
        }
        float bv = prb[n];
#pragma unroll
        for (int mt = 0; mt < 2; ++mt)
#pragma unroll
            for (int r = 0; r < 4; ++r)
                out[(size_t)(b * Pn + mt * 16 + quad * 4 + r) * En + n] =
                    acc[mt][r] + bv;
    }
}

extern "C" void kernel_launch(void* const* d_in, const int* in_sizes, int n_in,
                              void* d_out, int out_size, void* d_ws, size_t ws_size,
                              hipStream_t stream) {
    const float* x    = (const float*)d_in[0];
    const float* ipw  = (const float*)d_in[1];
    const float* ipb  = (const float*)d_in[2];
    const float* inw  = (const float*)d_in[3];
    const float* inb  = (const float*)d_in[4];
    const float* outw = (const float*)d_in[5];
    const float* outb = (const float*)d_in[6];
    const float* bw1  = (const float*)d_in[7];
    const float* bb1  = (const float*)d_in[8];
    const float* bw2  = (const float*)d_in[9];
    const float* bb2  = (const float*)d_in[10];
    const float* prw  = (const float*)d_in[11];
    const float* prb  = (const float*)d_in[12];

    char* base = (char*)d_ws;
    unsigned short* Qb  = (unsigned short*)base;
    unsigned short* Kb  = Qb + (size_t)8388608;
    float*          AO  = (float*)base;                                 // over Qb+Kb after attn
    unsigned short* Vt  = (unsigned short*)(base + (size_t)33554432);
    unsigned short* Po0 = (unsigned short*)(base + (size_t)50331648);
    unsigned short* Po1 = (unsigned short*)(base + (size_t)67108864);
    unsigned short* Wcb = (unsigned short*)(base + (size_t)83886080);   // 48 KB
    float*          bc  = (float*)(base + (size_t)83935232);            // 3 KB
    unsigned short* Wb  = (unsigned short*)(base + (size_t)83938304);   // 128 KB
    unsigned short* w1h = (unsigned short*)(base + (size_t)84069376);   // 16 KB
    unsigned short* w1l = (unsigned short*)(base + (size_t)84085760);   // 16 KB
    float*          L0  = (float*)(base + (size_t)84102144);            // 512 KB
    float*          L1  = (float*)(base + (size_t)84626432);            // 512 KB
    float*          bsc = (float*)(base + (size_t)85150720);            // 128 KB
    unsigned short* pwh = (unsigned short*)(base + (size_t)85286912);   // 128 KB
    unsigned short* pwl = (unsigned short*)(base + (size_t)85417984);   // 128 KB

    k_prep<<<99, 256, 0, stream>>>(ipw, ipb, inw, inb, Wcb, bc);
    k_qkv<<<864, 256, 0, stream>>>(x, Wcb, bc, outw, bw1, prw,
                                   Qb, Kb, Vt, Wb, w1h, w1l, pwh, pwl);
    k_attn<<<1024, 256, 0, stream>>>(Qb, Kb, Vt, Po0, Po1, L0, L1);
    k_out<<<512, 256, 0, stream>>>(Po0, Po1, L0, L1, Wb, outb, AO);
    k_bscore<<<256, 256, 0, stream>>>(AO, w1h, w1l, bb1, bw2, bb2, bsc);
    k_tail<<<32, 1024, 0, stream>>>(bsc, AO, pwh, pwl, prb, (float*)d_out);
}

// Round 10
// 217.025 us; speedup vs baseline: 1.9644x; 1.9644x over previous
//
#include <hip/hip_runtime.h>
#include <math.h>

constexpr int Bn  = 32;
constexpr int Tn  = 1024;
constexpr int INn = 32;
constexpr int En  = 256;
constexpr int Pn  = 32;

typedef short bf16x8 __attribute__((ext_vector_type(8)));
typedef float f32x4  __attribute__((ext_vector_type(4)));

__device__ __forceinline__ unsigned short f2bf(float f) {
    unsigned int b = __float_as_uint(f);
    b += 0x7FFF + ((b >> 16) & 1);          // RNE
    return (unsigned short)(b >> 16);
}
__device__ __forceinline__ float bf2f(unsigned short h) {
    return __uint_as_float(((unsigned int)h) << 16);
}
// pack trunc-bf16(lo), trunc-bf16(hi) in ONE v_perm (bytes [2,3] of each)
__device__ __forceinline__ unsigned int permpack(float lo, float hi) {
    return __builtin_amdgcn_perm(__float_as_uint(hi), __float_as_uint(lo),
                                 0x07060302u);
}

// ---------- K0: prep — Wcb bf16 = in_proj_w @ ip_w, bc ----------
__global__ __launch_bounds__(256) void k_prep(const float* __restrict__ ipw,
                                              const float* __restrict__ ipb,
                                              const float* __restrict__ inw,
                                              const float* __restrict__ inb,
                                              unsigned short* __restrict__ Wcb,
                                              float* __restrict__ bc) {
    int blk = blockIdx.x, tid = threadIdx.x;
    if (blk < 96) {
        int idx = blk * 256 + tid;
        int o = idx >> 5, i = idx & 31;
        const float* wr = inw + (size_t)o * En;
        float a0 = 0.f, a1 = 0.f;
        for (int e = 0; e < En; e += 2) {
            a0 += wr[e]     * ipw[(size_t)e * INn + i];
            a1 += wr[e + 1] * ipw[(size_t)(e + 1) * INn + i];
        }
        Wcb[(size_t)o * INn + i] = f2bf(a0 + a1);
    } else {
        int o = (blk - 96) * 256 + tid;
        const float* wr = inw + (size_t)o * En;
        float a = inb[o];
        for (int e = 0; e < En; ++e) a += wr[e] * ipb[e];
        bc[o] = a;
    }
}

// ---------- K1: qkv projection (0..511) + weight conversions (512..863) ----
__global__ __launch_bounds__(256, 2) void k_qkv(const float* __restrict__ x,
                                                const unsigned short* __restrict__ Wcb,
                                                const float* __restrict__ bc,
                                                const float* __restrict__ outw,
                                                const float* __restrict__ w1,
                                                const float* __restrict__ prw,
                                                unsigned short* __restrict__ Qb,
                                                unsigned short* __restrict__ Kb,
                                                unsigned short* __restrict__ Vt,
                                                unsigned short* __restrict__ Wb,
                                                unsigned short* __restrict__ w1h,
                                                unsigned short* __restrict__ w1l,
                                                unsigned short* __restrict__ pwh,
                                                unsigned short* __restrict__ pwl) {
    int tid = threadIdx.x;
    if (blockIdx.x >= 512) {
        int cb = blockIdx.x - 512;
        if (cb < 64) {
            int idx = cb * 256 + tid;              // 16384 float4s
            float4 a = *(const float4*)(outw + (size_t)idx * 4);
            unsigned int u0 = f2bf(a.x) | ((unsigned int)f2bf(a.y) << 16);
            unsigned int u1 = f2bf(a.z) | ((unsigned int)f2bf(a.w) << 16);
            *(uint2*)(Wb + (size_t)idx * 4) = make_uint2(u0, u1);
        } else if (cb < 96) {
            int idx = (cb - 64) * 256 + tid;       // 8192 elements
            float a = w1[idx];
            unsigned short h = f2bf(a);
            w1h[idx] = h;
            w1l[idx] = f2bf(a - bf2f(h));
        } else {
            int idx = (cb - 96) * 256 + tid;       // 65536 elements
            float a = prw[idx];
            unsigned short h = f2bf(a);
            pwh[idx] = h;
            pwl[idx] = f2bf(a - bf2f(h));
        }
        return;
    }
    int wv = tid >> 6, lane = tid & 63;
    int cl = lane & 15, quad = lane >> 4;
    int m0 = blockIdx.x * 64;
    int b = m0 >> 10, tl0 = m0 & 1023;
    int n0w = wv * 192;
    f32x4 zero4 = {0.f, 0.f, 0.f, 0.f};

    bf16x8 wfrag[12]; float bv[12];
#pragma unroll
    for (int nt = 0; nt < 12; ++nt) {
        int col = n0w + nt * 16 + cl;
        wfrag[nt] = *(const bf16x8*)(Wcb + (size_t)col * 32 + quad * 8);
        bv[nt] = bc[col];
    }
#pragma unroll
    for (int mt = 0; mt < 4; ++mt) {
        const float* xr = x + (size_t)(m0 + mt * 16 + cl) * 32 + quad * 8;
        float4 xa = *(const float4*)xr, xc = *(const float4*)(xr + 4);
        bf16x8 af;
        af[0] = (short)f2bf(xa.x); af[1] = (short)f2bf(xa.y);
        af[2] = (short)f2bf(xa.z); af[3] = (short)f2bf(xa.w);
        af[4] = (short)f2bf(xc.x); af[5] = (short)f2bf(xc.y);
        af[6] = (short)f2bf(xc.z); af[7] = (short)f2bf(xc.w);
        f32x4 acc[12];
#pragma unroll
        for (int nt = 0; nt < 12; ++nt)
            acc[nt] = __builtin_amdgcn_mfma_f32_16x16x32_bf16(af, wfrag[nt], zero4, 0, 0, 0);
        int tloc = tl0 + mt * 16 + quad * 4;
#pragma unroll
        for (int nt = 0; nt < 12; ++nt) {
            int col = n0w + nt * 16 + cl;
            int slot = col >> 8, c = col & 255;
            int h = c >> 6, d = c & 63;
            int bh = b * 4 + h;
            if (slot == 2) {
                unsigned int u0 = f2bf(acc[nt][0] + bv[nt]) |
                                  ((unsigned int)f2bf(acc[nt][1] + bv[nt]) << 16);
                unsigned int u1 = f2bf(acc[nt][2] + bv[nt]) |
                                  ((unsigned int)f2bf(acc[nt][3] + bv[nt]) << 16);
                *(uint2*)(Vt + ((size_t)bh * 64 + d) * 1024 + tloc) = make_uint2(u0, u1);
            } else {
                unsigned short* dst = (slot ? Kb : Qb) +
                                      ((size_t)bh * 1024 + tloc) * 64 + d;
#pragma unroll
                for (int r = 0; r < 4; ++r)
                    dst[(size_t)r * 64] = f2bf(acc[nt][r] + bv[nt]);
            }
        }
    }
}

// ---------- K2: MFMA flash attention — R8-proven 32q/wave, block K-split ----
// grid 2048: bh = blk & 127, qb = (blk>>7)&7, half = blk>>10.  VGPR ~60.
__global__ __launch_bounds__(256, 4) void k_attn(const unsigned short* __restrict__ Qb,
                                                 const unsigned short* __restrict__ Kb,
                                                 const unsigned short* __restrict__ Vt,
                                                 unsigned short* __restrict__ Po0,
                                                 unsigned short* __restrict__ Po1,
                                                 float* __restrict__ L0,
                                                 float* __restrict__ L1) {
    __shared__ unsigned short Ks[64][72];
    __shared__ unsigned short Vs[64][72];
    __shared__ __align__(16) unsigned short Pl[4][2][16][40];
    int blk = blockIdx.x;
    int bh = blk & 127;
    int r_ = blk >> 7;
    int qb = r_ & 7, half = r_ >> 3;
    int b = bh >> 2, h = bh & 3;
    int tid = threadIdx.x;
    int wv = tid >> 6, lane = tid & 63;
    int cl = lane & 15, quad = lane >> 4;
    int qbase = qb * 128 + wv * 32;
    const float SCL = 0.18033688f;                 // 0.125 * log2(e)

    f32x4 zero4 = {0.f, 0.f, 0.f, 0.f};
    bf16x8 qfrag[2][2];
#pragma unroll
    for (int tt = 0; tt < 2; ++tt)
#pragma unroll
        for (int ch = 0; ch < 2; ++ch)
            qfrag[tt][ch] = *(const bf16x8*)(Qb +
                ((size_t)bh * 1024 + qbase + tt * 16 + cl) * 64 + ch * 32 + quad * 8);
    f32x4 acc[2][4];
#pragma unroll
    for (int tt = 0; tt < 2; ++tt)
#pragma unroll
        for (int dt = 0; dt < 4; ++dt) acc[tt][dt] = zero4;
    float l[2] = {0.f, 0.f};

    const unsigned short* Kbase = Kb + (size_t)bh * 65536;
    const unsigned short* Vbase = Vt + (size_t)bh * 65536;

    for (int kt = 0; kt < 8; ++kt) {
        int ktt = half * 8 + kt;
#pragma unroll
        for (int r = 0; r < 2; ++r) {
            int idx = r * 256 + tid; int row = idx >> 3, c16 = idx & 7;
            *(uint4*)&Ks[row][c16 * 8] =
                *(const uint4*)(Kbase + (size_t)(ktt * 64 + row) * 64 + c16 * 8);
            *(uint4*)&Vs[row][c16 * 8] =
                *(const uint4*)(Vbase + (size_t)row * 1024 + ktt * 64 + c16 * 8);
        }
        __syncthreads();
#pragma unroll
        for (int c = 0; c < 2; ++c) {
            bf16x8 ka0 = *(const bf16x8*)&Ks[c * 32 + cl][quad * 8];
            bf16x8 ka1 = *(const bf16x8*)&Ks[c * 32 + cl][32 + quad * 8];
            bf16x8 kb0 = *(const bf16x8*)&Ks[c * 32 + 16 + cl][quad * 8];
            bf16x8 kb1 = *(const bf16x8*)&Ks[c * 32 + 16 + cl][32 + quad * 8];
            bf16x8 va[4];
#pragma unroll
            for (int dt = 0; dt < 4; ++dt)
                va[dt] = *(const bf16x8*)&Vs[dt * 16 + cl][c * 32 + quad * 8];
#pragma unroll
            for (int tt = 0; tt < 2; ++tt) {
                f32x4 s0 = __builtin_amdgcn_mfma_f32_16x16x32_bf16(ka0, qfrag[tt][0], zero4, 0, 0, 0);
                s0 = __builtin_amdgcn_mfma_f32_16x16x32_bf16(ka1, qfrag[tt][1], s0, 0, 0, 0);
                f32x4 s1 = __builtin_amdgcn_mfma_f32_16x16x32_bf16(kb0, qfrag[tt][0], zero4, 0, 0, 0);
                s1 = __builtin_amdgcn_mfma_f32_16x16x32_bf16(kb1, qfrag[tt][1], s1, 0, 0, 0);
                float p0 = exp2f(SCL * s0[0]), p1 = exp2f(SCL * s0[1]);
                float p2 = exp2f(SCL * s0[2]), p3 = exp2f(SCL * s0[3]);
                float p4 = exp2f(SCL * s1[0]), p5 = exp2f(SCL * s1[1]);
                float p6 = exp2f(SCL * s1[2]), p7 = exp2f(SCL * s1[3]);
                unsigned int w0 = permpack(p0, p1);
                unsigned int w1 = permpack(p2, p3);
                unsigned int w2 = permpack(p4, p5);
                unsigned int w3 = permpack(p6, p7);
                // l from the SAME truncated values -> bias cancels in o/l
                l[tt] += ((__uint_as_float(w0 << 16) + __uint_as_float(w0 & 0xffff0000u)) +
                          (__uint_as_float(w1 << 16) + __uint_as_float(w1 & 0xffff0000u))) +
                         ((__uint_as_float(w2 << 16) + __uint_as_float(w2 & 0xffff0000u)) +
                          (__uint_as_float(w3 << 16) + __uint_as_float(w3 & 0xffff0000u)));
                *(uint2*)&Pl[wv][tt][cl][quad * 4]      = make_uint2(w0, w1);
                *(uint2*)&Pl[wv][tt][cl][16 + quad * 4] = make_uint2(w2, w3);
            }
            asm volatile("s_waitcnt lgkmcnt(0)" ::: "memory");
#pragma unroll
            for (int tt = 0; tt < 2; ++tt) {
                bf16x8 pf = *(const bf16x8*)&Pl[wv][tt][cl][quad * 8];
#pragma unroll
                for (int dt = 0; dt < 4; ++dt)
                    acc[tt][dt] = __builtin_amdgcn_mfma_f32_16x16x32_bf16(pf, va[dt], acc[tt][dt], 0, 0, 0);
            }
        }
        __syncthreads();
    }
#pragma unroll
    for (int tt = 0; tt < 2; ++tt) {
        l[tt] += __shfl_xor(l[tt], 16);
        l[tt] += __shfl_xor(l[tt], 32);
    }
    unsigned short* Po = half ? Po1 : Po0;
    float* Lp = half ? L1 : L0;
#pragma unroll
    for (int tt = 0; tt < 2; ++tt) {
#pragma unroll
        for (int r = 0; r < 4; ++r) {
            size_t row = (size_t)(b * 1024 + qbase + tt * 16 + quad * 4 + r) * En;
#pragma unroll
            for (int dt = 0; dt < 4; ++dt)
                Po[row + h * 64 + dt * 16 + cl] = f2bf(acc[tt][dt][r]);
        }
    }
    if (quad == 0) {
#pragma unroll
        for (int tt = 0; tt < 2; ++tt)
            Lp[bh * 1024 + qbase + tt * 16 + cl] = l[tt];
    }
}

// ---------- K3: combine + out-proj + FUSED boundary-MLP ----------
// Block owns 64 complete AO rows -> bscore computed in-kernel (2 MFMAs, w1 hi/lo).
__global__ __launch_bounds__(256) void k_out(const unsigned short* __restrict__ Po0,
                                             const unsigned short* __restrict__ Po1,
                                             const float* __restrict__ L0,
                                             const float* __restrict__ L1,
                                             const unsigned short* __restrict__ Wb,
                                             const float* __restrict__ bias,
                                             const unsigned short* __restrict__ w1h,
                                             const unsigned short* __restrict__ w1l,
                                             const float* __restrict__ b1,
                                             const float* __restrict__ w2,
                                             const float* __restrict__ b2,
                                             float* __restrict__ AO,
                                             float* __restrict__ bsc) {
    __shared__ unsigned short As[64][32];
    __shared__ unsigned short Bs[256][32];
    __shared__ unsigned short Ah[64][258];        // full-width bf16 AO rows
    int tid = threadIdx.x;
    int wv = tid >> 6, lane = tid & 63;
    int cl = lane & 15, quad = lane >> 4;
    size_t m0 = (size_t)blockIdx.x * 64;

    f32x4 acc[4][4];
#pragma unroll
    for (int mt = 0; mt < 4; ++mt)
#pragma unroll
        for (int nt = 0; nt < 4; ++nt) acc[mt][nt] = {0.f, 0.f, 0.f, 0.f};

    for (int kt = 0; kt < 8; ++kt) {
        if (kt) __syncthreads();
        {
            int row = tid >> 2, c4 = tid & 3;
            size_t g = (m0 + row) * En + kt * 32 + c4 * 8;
            uint4 u0 = *(const uint4*)(Po0 + g);
            uint4 u1 = *(const uint4*)(Po1 + g);
            int gt = (int)(m0 + row);
            int li = ((gt >> 10) * 4 + (kt >> 1)) * 1024 + (gt & 1023);
            float linv = 1.f / (L0[li] + L1[li]);
            unsigned int a0[4] = {u0.x, u0.y, u0.z, u0.w};
            unsigned int a1[4] = {u1.x, u1.y, u1.z, u1.w};
            unsigned int w[4];
#pragma unroll
            for (int j = 0; j < 4; ++j) {
                float lo = (bf2f((unsigned short)(a0[j] & 0xffff)) +
                            bf2f((unsigned short)(a1[j] & 0xffff))) * linv;
                float hi = (bf2f((unsigned short)(a0[j] >> 16)) +
                            bf2f((unsigned short)(a1[j] >> 16))) * linv;
                w[j] = f2bf(lo) | ((unsigned int)f2bf(hi) << 16);
            }
            *(uint4*)&As[row][c4 * 8] = make_uint4(w[0], w[1], w[2], w[3]);
        }
#pragma unroll
        for (int j = 0; j < 4; ++j) {
            int lin = j * 256 + tid; int n = lin >> 2, c = lin & 3;
            *(uint4*)&Bs[n][c * 8] =
                *(const uint4*)(Wb + (size_t)n * En + kt * 32 + c * 8);
        }
        __syncthreads();
        bf16x8 af[4], bfr[4];
#pragma unroll
        for (int mt = 0; mt < 4; ++mt)
            af[mt] = *(const bf16x8*)&As[mt * 16 + cl][quad * 8];
#pragma unroll
        for (int nt = 0; nt < 4; ++nt)
            bfr[nt] = *(const bf16x8*)&Bs[wv * 64 + nt * 16 + cl][quad * 8];
#pragma unroll
        for (int mt = 0; mt < 4; ++mt)
#pragma unroll
            for (int nt = 0; nt < 4; ++nt)
                acc[mt][nt] = __builtin_amdgcn_mfma_f32_16x16x32_bf16(af[mt], bfr[nt], acc[mt][nt], 0, 0, 0);
    }
    float bv[4];
#pragma unroll
    for (int nt = 0; nt < 4; ++nt) bv[nt] = bias[wv * 64 + nt * 16 + cl];
    __syncthreads();                               // As/Bs done; Ah phase begins
#pragma unroll
    for (int mt = 0; mt < 4; ++mt)
#pragma unroll
        for (int nt = 0; nt < 4; ++nt)
#pragma unroll
            for (int r = 0; r < 4; ++r) {
                float a = acc[mt][nt][r] + bv[nt];
                AO[(m0 + mt * 16 + quad * 4 + r) * En + wv * 64 + nt * 16 + cl] = a;
                Ah[mt * 16 + quad * 4 + r][wv * 64 + nt * 16 + cl] = f2bf(a);
            }
    __syncthreads();
    // boundary MLP: h1 = Ah @ w1^T (2 MFMAs: Ah*w1h + Ah*w1l), relu, *w2, sigmoid
    {
        f32x4 hacc[2] = {{0.f, 0.f, 0.f, 0.f}, {0.f, 0.f, 0.f, 0.f}};
        for (int kt = 0; kt < 8; ++kt) {
            bf16x8 ah = *(const bf16x8*)&Ah[wv * 16 + cl][kt * 32 + quad * 8];
#pragma unroll
            for (int nt = 0; nt < 2; ++nt) {
                size_t off = (size_t)(nt * 16 + cl) * En + kt * 32 + quad * 8;
                bf16x8 bh_ = *(const bf16x8*)(w1h + off);
                bf16x8 bl_ = *(const bf16x8*)(w1l + off);
                hacc[nt] = __builtin_amdgcn_mfma_f32_16x16x32_bf16(ah, bh_, hacc[nt], 0, 0, 0);
                hacc[nt] = __builtin_amdgcn_mfma_f32_16x16x32_bf16(ah, bl_, hacc[nt], 0, 0, 0);
            }
        }
        float b1v[2] = {b1[cl], b1[16 + cl]};
        float w2v[2] = {w2[cl], w2[16 + cl]};
        float b2v = b2[0];
        f32x4 z;
#pragma unroll
        for (int r = 0; r < 4; ++r)
            z[r] = fmaxf(hacc[0][r] + b1v[0], 0.f) * w2v[0] +
                   fmaxf(hacc[1][r] + b1v[1], 0.f) * w2v[1];
#pragma unroll
        for (int d = 1; d < 16; d <<= 1)
#pragma unroll
            for (int r = 0; r < 4; ++r) z[r] += __shfl_xor(z[r], d);
        if (cl == 0) {
#pragma unroll
            for (int r = 0; r < 4; ++r)
                bsc[m0 + wv * 16 + quad * 4 + r] =
                    1.f / (1.f + __expf(-(z[r] + b2v)));
        }
    }
}

// ---------- K4: pool with FUSED in-block scan (redundant per block, cheap) --
// grid (32 p, 32 b), 256 thr. Scan is deterministic & identical across the
// 32 blocks of a batch -> consistent segs.
__global__ __launch_bounds__(256) void k_pool(const float* __restrict__ bsc,
                                              const float* __restrict__ AO,
                                              float* __restrict__ PE) {
    __shared__ float pre[1024];
    __shared__ float wsl[4];
    __shared__ float stot_s;
    __shared__ int   segs[33];
    int b = blockIdx.y, p = blockIdx.x, t = threadIdx.x;
    int lane = t & 63, wv = t >> 6;
    float4 v = *(const float4*)(bsc + b * 1024 + t * 4);
    float s0 = v.x, s1 = s0 + v.y, s2 = s1 + v.z, s3 = s2 + v.w;
    float ts = s3, sc = ts;
#pragma unroll
    for (int d = 1; d < 64; d <<= 1) {
        float y = __shfl_up(sc, d);
        if (lane >= d) sc += y;
    }
    if (lane == 63) wsl[wv] = sc;
    __syncthreads();
    if (t == 0) {
        float s = 0.f;
        for (int i = 0; i < 4; ++i) { float tmp = wsl[i]; wsl[i] = s; s += tmp; }
        stot_s = s;
    }
    __syncthreads();
    float base = wsl[wv] + (sc - ts);
    pre[t * 4 + 0] = base + s0;
    pre[t * 4 + 1] = base + s1;
    pre[t * 4 + 2] = base + s2;
    pre[t * 4 + 3] = base + s3;
    __syncthreads();
    float denom = stot_s + 1e-6f;
    int lastpid = 0;
#pragma unroll
    for (int i = 0; i < 4; ++i) {
        int t4 = t * 4 + i;
        int pid = min((int)floorf(pre[t4] / denom * 32.0f), 31);
        int pidprev = (t4 == 0) ? -1
                      : min((int)floorf(pre[t4 - 1] / denom * 32.0f), 31);
        for (int pp = pidprev + 1; pp <= pid; ++pp) segs[pp] = t4;
        lastpid = pid;
    }
    if (t == 255)
        for (int pp = lastpid + 1; pp <= 32; ++pp) segs[pp] = Tn;
    __syncthreads();
    int s = segs[p], e = segs[p + 1];
    float sum = 0.f;
    for (int tk = s; tk < e; ++tk)
        sum += AO[((size_t)b * Tn + tk) * En + t];
    PE[(size_t)(b * Pn + p) * En + t] = sum / fmaxf((float)(e - s), 1.f);
}

// ---------- K5: out = PE @ prw^T + prb  (hi/lo-split bf16 MFMA) ----------
__global__ __launch_bounds__(256) void k_final(const float* __restrict__ PE,
                                               const unsigned short* __restrict__ pwh,
                                               const unsigned short* __restrict__ pwl,
                                               const float* __restrict__ prb,
                                               float* __restrict__ out) {
    __shared__ unsigned short Ahs[64][40];
    __shared__ unsigned short Als[64][40];
    int tid = threadIdx.x;
    int wv = tid >> 6, lane = tid & 63;
    int cl = lane & 15, quad = lane >> 4;
    int m0 = blockIdx.x * 64;

    f32x4 acc[4][4];
#pragma unroll
    for (int mt = 0; mt < 4; ++mt)
#pragma unroll
        for (int nt = 0; nt < 4; ++nt) acc[mt][nt] = {0.f, 0.f, 0.f, 0.f};

    for (int kt = 0; kt < 8; ++kt) {
        if (kt) __syncthreads();
        {
            int row = tid >> 2, c8 = (tid & 3) * 8;
            const float* src = PE + (size_t)(m0 + row) * En + kt * 32 + c8;
            float4 a = *(const float4*)src, b4 = *(const float4*)(src + 4);
            float v[8] = {a.x, a.y, a.z, a.w, b4.x, b4.y, b4.z, b4.w};
            unsigned int hw[4], lw[4];
#pragma unroll
            for (int j = 0; j < 4; ++j) {
                unsigned short h0 = f2bf(v[2 * j]), h1 = f2bf(v[2 * j + 1]);
                unsigned short q0 = f2bf(v[2 * j] - bf2f(h0));
                unsigned short q1 = f2bf(v[2 * j + 1] - bf2f(h1));
                hw[j] = h0 | ((unsigned int)h1 << 16);
                lw[j] = q0 | ((unsigned int)q1 << 16);
            }
            *(uint4*)&Ahs[row][c8] = make_uint4(hw[0], hw[1], hw[2], hw[3]);
            *(uint4*)&Als[row][c8] = make_uint4(lw[0], lw[1], lw[2], lw[3]);
        }
        __syncthreads();
        bf16x8 ah[4], al[4], bh_[4], bl_[4];
#pragma unroll
        for (int mt = 0; mt < 4; ++mt) {
            ah[mt] = *(const bf16x8*)&Ahs[mt * 16 + cl][quad * 8];
            al[mt] = *(const bf16x8*)&Als[mt * 16 + cl][quad * 8];
        }
#pragma unroll
        for (int nt = 0; nt < 4; ++nt) {
            size_t off = (size_t)(wv * 64 + nt * 16 + cl) * En + kt * 32 + quad * 8;
            bh_[nt] = *(const bf16x8*)(pwh + off);
            bl_[nt] = *(const bf16x8*)(pwl + off);
        }
#pragma unroll
        for (int mt = 0; mt < 4; ++mt)
#pragma unroll
            for (int nt = 0; nt < 4; ++nt) {
                acc[mt][nt] = __builtin_amdgcn_mfma_f32_16x16x32_bf16(ah[mt], bh_[nt], acc[mt][nt], 0, 0, 0);
                acc[mt][nt] = __builtin_amdgcn_mfma_f32_16x16x32_bf16(ah[mt], bl_[nt], acc[mt][nt], 0, 0, 0);
                acc[mt][nt] = __builtin_amdgcn_mfma_f32_16x16x32_bf16(al[mt], bh_[nt], acc[mt][nt], 0, 0, 0);
            }
    }
    float bv[4];
#pragma unroll
    for (int nt = 0; nt < 4; ++nt) bv[nt] = prb[wv * 64 + nt * 16 + cl];
#pragma unroll
    for (int mt = 0; mt < 4; ++mt)
#pragma unroll
        for (int nt = 0; nt < 4; ++nt)
#pragma unroll
            for (int r = 0; r < 4; ++r)
                out[(size_t)(m0 + mt * 16 + quad * 4 + r) * En + wv * 64 + nt * 16 + cl] =
                    acc[mt][nt][r] + bv[nt];
}

extern "C" void kernel_launch(void* const* d_in, const int* in_sizes, int n_in,
                              void* d_out, int out_size, void* d_ws, size_t ws_size,
                              hipStream_t stream) {
    const float* x    = (const float*)d_in[0];
    const float* ipw  = (const float*)d_in[1];
    const float* ipb  = (const float*)d_in[2];
    const float* inw  = (const float*)d_in[3];
    const float* inb  = (const float*)d_in[4];
    const float* outw = (const float*)d_in[5];
    const float* outb = (const float*)d_in[6];
    const float* bw1  = (const float*)d_in[7];
    const float* bb1  = (const float*)d_in[8];
    const float* bw2  = (const float*)d_in[9];
    const float* bb2  = (const float*)d_in[10];
    const float* prw  = (const float*)d_in[11];
    const float* prb  = (const float*)d_in[12];

    char* base = (char*)d_ws;
    unsigned short* Qb  = (unsigned short*)base;
    unsigned short* Kb  = Qb + (size_t)8388608;
    float*          AO  = (float*)base;                                 // over Qb+Kb after attn
    unsigned short* Vt  = (unsigned short*)(base + (size_t)33554432);
    float*          PE  = (float*)(base + (size_t)33554432);            // over Vt after attn
    unsigned short* Po0 = (unsigned short*)(base + (size_t)50331648);
    unsigned short* Po1 = (unsigned short*)(base + (size_t)67108864);
    unsigned short* Wcb = (unsigned short*)(base + (size_t)83886080);   // 48 KB
    float*          bc  = (float*)(base + (size_t)83935232);            // 3 KB
    unsigned short* Wb  = (unsigned short*)(base + (size_t)83938304);   // 128 KB
    unsigned short* w1h = (unsigned short*)(base + (size_t)84069376);   // 16 KB
    unsigned short* w1l = (unsigned short*)(base + (size_t)84085760);   // 16 KB
    float*          L0  = (float*)(base + (size_t)84102144);            // 512 KB
    float*          L1  = (float*)(base + (size_t)84626432);            // 512 KB
    float*          bsc = (float*)(base + (size_t)85150720);            // 128 KB
    unsigned short* pwh = (unsigned short*)(base + (size_t)85286912);   // 128 KB
    unsigned short* pwl = (unsigned short*)(base + (size_t)85417984);   // 128 KB

    k_prep<<<99, 256, 0, stream>>>(ipw, ipb, inw, inb, Wcb, bc);
    k_qkv<<<864, 256, 0, stream>>>(x, Wcb, bc, outw, bw1, prw,
                                   Qb, Kb, Vt, Wb, w1h, w1l, pwh, pwl);
    k_attn<<<2048, 256, 0, stream>>>(Qb, Kb, Vt, Po0, Po1, L0, L1);
    k_out<<<512, 256, 0, stream>>>(Po0, Po1, L0, L1, Wb, outb,
                                   w1h, w1l, bb1, bw2, bb2, AO, bsc);
    k_pool<<<dim3(32, 32), 256, 0, stream>>>(bsc, AO, PE);
    k_final<<<16, 256, 0, stream>>>(PE, pwh, pwl, prb, (float*)d_out);
}

// Round 11
// 206.709 us; speedup vs baseline: 2.0625x; 1.0499x over previous
//
#include <hip/hip_runtime.h>
#include <math.h>

constexpr int Bn  = 32;
constexpr int Tn  = 1024;
constexpr int INn = 32;
constexpr int En  = 256;
constexpr int Pn  = 32;

typedef short bf16x8 __attribute__((ext_vector_type(8)));
typedef float f32x4  __attribute__((ext_vector_type(4)));

__device__ __forceinline__ unsigned short f2bf(float f) {
    unsigned int b = __float_as_uint(f);
    b += 0x7FFF + ((b >> 16) & 1);          // RNE
    return (unsigned short)(b >> 16);
}
__device__ __forceinline__ float bf2f(unsigned short h) {
    return __uint_as_float(((unsigned int)h) << 16);
}
// pack trunc-bf16(lo), trunc-bf16(hi) in ONE v_perm (bytes [2,3] of each)
__device__ __forceinline__ unsigned int permpack(float lo, float hi) {
    return __builtin_amdgcn_perm(__float_as_uint(hi), __float_as_uint(lo),
                                 0x07060302u);
}

// ---------- K0: prep — Wcb bf16 = in_proj_w @ ip_w, bc ----------
__global__ __launch_bounds__(256) void k_prep(const float* __restrict__ ipw,
                                              const float* __restrict__ ipb,
                                              const float* __restrict__ inw,
                                              const float* __restrict__ inb,
                                              unsigned short* __restrict__ Wcb,
                                              float* __restrict__ bc) {
    int blk = blockIdx.x, tid = threadIdx.x;
    if (blk < 96) {
        int idx = blk * 256 + tid;
        int o = idx >> 5, i = idx & 31;
        const float* wr = inw + (size_t)o * En;
        float a0 = 0.f, a1 = 0.f;
        for (int e = 0; e < En; e += 2) {
            a0 += wr[e]     * ipw[(size_t)e * INn + i];
            a1 += wr[e + 1] * ipw[(size_t)(e + 1) * INn + i];
        }
        Wcb[(size_t)o * INn + i] = f2bf(a0 + a1);
    } else {
        int o = (blk - 96) * 256 + tid;
        const float* wr = inw + (size_t)o * En;
        float a = inb[o];
        for (int e = 0; e < En; ++e) a += wr[e] * ipb[e];
        bc[o] = a;
    }
}

// ---------- K1: qkv projection (0..511) + weight conversions (512..863) ----
__global__ __launch_bounds__(256, 2) void k_qkv(const float* __restrict__ x,
                                                const unsigned short* __restrict__ Wcb,
                                                const float* __restrict__ bc,
                                                const float* __restrict__ outw,
                                                const float* __restrict__ w1,
                                                const float* __restrict__ prw,
                                                unsigned short* __restrict__ Qb,
                                                unsigned short* __restrict__ Kb,
                                                unsigned short* __restrict__ Vt,
                                                unsigned short* __restrict__ Wb,
                                                unsigned short* __restrict__ w1h,
                                                unsigned short* __restrict__ w1l,
                                                unsigned short* __restrict__ pwh,
                                                unsigned short* __restrict__ pwl) {
    int tid = threadIdx.x;
    if (blockIdx.x >= 512) {
        int cb = blockIdx.x - 512;
        if (cb < 64) {
            int idx = cb * 256 + tid;              // 16384 float4s
            float4 a = *(const float4*)(outw + (size_t)idx * 4);
            unsigned int u0 = f2bf(a.x) | ((unsigned int)f2bf(a.y) << 16);
            unsigned int u1 = f2bf(a.z) | ((unsigned int)f2bf(a.w) << 16);
            *(uint2*)(Wb + (size_t)idx * 4) = make_uint2(u0, u1);
        } else if (cb < 96) {
            int idx = (cb - 64) * 256 + tid;       // 8192 elements
            float a = w1[idx];
            unsigned short h = f2bf(a);
            w1h[idx] = h;
            w1l[idx] = f2bf(a - bf2f(h));
        } else {
            int idx = (cb - 96) * 256 + tid;       // 65536 elements
            float a = prw[idx];
            unsigned short h = f2bf(a);
            pwh[idx] = h;
            pwl[idx] = f2bf(a - bf2f(h));
        }
        return;
    }
    int wv = tid >> 6, lane = tid & 63;
    int cl = lane & 15, quad = lane >> 4;
    int m0 = blockIdx.x * 64;
    int b = m0 >> 10, tl0 = m0 & 1023;
    int n0w = wv * 192;
    f32x4 zero4 = {0.f, 0.f, 0.f, 0.f};

    bf16x8 wfrag[12]; float bv[12];
#pragma unroll
    for (int nt = 0; nt < 12; ++nt) {
        int col = n0w + nt * 16 + cl;
        wfrag[nt] = *(const bf16x8*)(Wcb + (size_t)col * 32 + quad * 8);
        bv[nt] = bc[col];
    }
#pragma unroll
    for (int mt = 0; mt < 4; ++mt) {
        const float* xr = x + (size_t)(m0 + mt * 16 + cl) * 32 + quad * 8;
        float4 xa = *(const float4*)xr, xc = *(const float4*)(xr + 4);
        bf16x8 af;
        af[0] = (short)f2bf(xa.x); af[1] = (short)f2bf(xa.y);
        af[2] = (short)f2bf(xa.z); af[3] = (short)f2bf(xa.w);
        af[4] = (short)f2bf(xc.x); af[5] = (short)f2bf(xc.y);
        af[6] = (short)f2bf(xc.z); af[7] = (short)f2bf(xc.w);
        f32x4 acc[12];
#pragma unroll
        for (int nt = 0; nt < 12; ++nt)
            acc[nt] = __builtin_amdgcn_mfma_f32_16x16x32_bf16(af, wfrag[nt], zero4, 0, 0, 0);
        int tloc = tl0 + mt * 16 + quad * 4;
#pragma unroll
        for (int nt = 0; nt < 12; ++nt) {
            int col = n0w + nt * 16 + cl;
            int slot = col >> 8, c = col & 255;
            int h = c >> 6, d = c & 63;
            int bh = b * 4 + h;
            if (slot == 2) {
                unsigned int u0 = f2bf(acc[nt][0] + bv[nt]) |
                                  ((unsigned int)f2bf(acc[nt][1] + bv[nt]) << 16);
                unsigned int u1 = f2bf(acc[nt][2] + bv[nt]) |
                                  ((unsigned int)f2bf(acc[nt][3] + bv[nt]) << 16);
                *(uint2*)(Vt + ((size_t)bh * 64 + d) * 1024 + tloc) = make_uint2(u0, u1);
            } else {
                unsigned short* dst = (slot ? Kb : Qb) +
                                      ((size_t)bh * 1024 + tloc) * 64 + d;
#pragma unroll
                for (int r = 0; r < 4; ++r)
                    dst[(size_t)r * 64] = f2bf(acc[nt][r] + bv[nt]);
            }
        }
    }
}

// ---------- K2: MFMA flash attention — 32q/wave, block K-split ----------
// grid 2048: bh = blk & 127, qb = (blk>>7)&7, half = blk>>10.  VGPR ~60.
// NOTE: __expf ONLY — libm exp2f costs +10 µs in guarded VALU ops (R10 A/B).
__global__ __launch_bounds__(256, 4) void k_attn(const unsigned short* __restrict__ Qb,
                                                 const unsigned short* __restrict__ Kb,
                                                 const unsigned short* __restrict__ Vt,
                                                 unsigned short* __restrict__ Po0,
                                                 unsigned short* __restrict__ Po1,
                                                 float* __restrict__ L0,
                                                 float* __restrict__ L1) {
    __shared__ unsigned short Ks[64][72];
    __shared__ unsigned short Vs[64][72];
    __shared__ __align__(16) unsigned short Pl[4][2][16][40];
    int blk = blockIdx.x;
    int bh = blk & 127;
    int r_ = blk >> 7;
    int qb = r_ & 7, half = r_ >> 3;
    int b = bh >> 2, h = bh & 3;
    int tid = threadIdx.x;
    int wv = tid >> 6, lane = tid & 63;
    int cl = lane & 15, quad = lane >> 4;
    int qbase = qb * 128 + wv * 32;

    f32x4 zero4 = {0.f, 0.f, 0.f, 0.f};
    bf16x8 qfrag[2][2];
#pragma unroll
    for (int tt = 0; tt < 2; ++tt)
#pragma unroll
        for (int ch = 0; ch < 2; ++ch)
            qfrag[tt][ch] = *(const bf16x8*)(Qb +
                ((size_t)bh * 1024 + qbase + tt * 16 + cl) * 64 + ch * 32 + quad * 8);
    f32x4 acc[2][4];
#pragma unroll
    for (int tt = 0; tt < 2; ++tt)
#pragma unroll
        for (int dt = 0; dt < 4; ++dt) acc[tt][dt] = zero4;
    float l[2] = {0.f, 0.f};

    const unsigned short* Kbase = Kb + (size_t)bh * 65536;
    const unsigned short* Vbase = Vt + (size_t)bh * 65536;

    for (int kt = 0; kt < 8; ++kt) {
        int ktt = half * 8 + kt;
#pragma unroll
        for (int r = 0; r < 2; ++r) {
            int idx = r * 256 + tid; int row = idx >> 3, c16 = idx & 7;
            *(uint4*)&Ks[row][c16 * 8] =
                *(const uint4*)(Kbase + (size_t)(ktt * 64 + row) * 64 + c16 * 8);
            *(uint4*)&Vs[row][c16 * 8] =
                *(const uint4*)(Vbase + (size_t)row * 1024 + ktt * 64 + c16 * 8);
        }
        __syncthreads();
#pragma unroll
        for (int c = 0; c < 2; ++c) {
            bf16x8 ka0 = *(const bf16x8*)&Ks[c * 32 + cl][quad * 8];
            bf16x8 ka1 = *(const bf16x8*)&Ks[c * 32 + cl][32 + quad * 8];
            bf16x8 kb0 = *(const bf16x8*)&Ks[c * 32 + 16 + cl][quad * 8];
            bf16x8 kb1 = *(const bf16x8*)&Ks[c * 32 + 16 + cl][32 + quad * 8];
            bf16x8 va[4];
#pragma unroll
            for (int dt = 0; dt < 4; ++dt)
                va[dt] = *(const bf16x8*)&Vs[dt * 16 + cl][c * 32 + quad * 8];
#pragma unroll
            for (int tt = 0; tt < 2; ++tt) {
                f32x4 s0 = __builtin_amdgcn_mfma_f32_16x16x32_bf16(ka0, qfrag[tt][0], zero4, 0, 0, 0);
                s0 = __builtin_amdgcn_mfma_f32_16x16x32_bf16(ka1, qfrag[tt][1], s0, 0, 0, 0);
                f32x4 s1 = __builtin_amdgcn_mfma_f32_16x16x32_bf16(kb0, qfrag[tt][0], zero4, 0, 0, 0);
                s1 = __builtin_amdgcn_mfma_f32_16x16x32_bf16(kb1, qfrag[tt][1], s1, 0, 0, 0);
                float p0 = __expf(0.125f * s0[0]), p1 = __expf(0.125f * s0[1]);
                float p2 = __expf(0.125f * s0[2]), p3 = __expf(0.125f * s0[3]);
                float p4 = __expf(0.125f * s1[0]), p5 = __expf(0.125f * s1[1]);
                float p6 = __expf(0.125f * s1[2]), p7 = __expf(0.125f * s1[3]);
                unsigned int w0 = permpack(p0, p1);
                unsigned int w1 = permpack(p2, p3);
                unsigned int w2 = permpack(p4, p5);
                unsigned int w3 = permpack(p6, p7);
                // l from the SAME truncated values -> bias cancels in o/l
                l[tt] += ((__uint_as_float(w0 << 16) + __uint_as_float(w0 & 0xffff0000u)) +
                          (__uint_as_float(w1 << 16) + __uint_as_float(w1 & 0xffff0000u))) +
                         ((__uint_as_float(w2 << 16) + __uint_as_float(w2 & 0xffff0000u)) +
                          (__uint_as_float(w3 << 16) + __uint_as_float(w3 & 0xffff0000u)));
                *(uint2*)&Pl[wv][tt][cl][quad * 4]      = make_uint2(w0, w1);
                *(uint2*)&Pl[wv][tt][cl][16 + quad * 4] = make_uint2(w2, w3);
            }
            asm volatile("s_waitcnt lgkmcnt(0)" ::: "memory");
#pragma unroll
            for (int tt = 0; tt < 2; ++tt) {
                bf16x8 pf = *(const bf16x8*)&Pl[wv][tt][cl][quad * 8];
#pragma unroll
                for (int dt = 0; dt < 4; ++dt)
                    acc[tt][dt] = __builtin_amdgcn_mfma_f32_16x16x32_bf16(pf, va[dt], acc[tt][dt], 0, 0, 0);
            }
        }
        __syncthreads();
    }
#pragma unroll
    for (int tt = 0; tt < 2; ++tt) {
        l[tt] += __shfl_xor(l[tt], 16);
        l[tt] += __shfl_xor(l[tt], 32);
    }
    unsigned short* Po = half ? Po1 : Po0;
    float* Lp = half ? L1 : L0;
#pragma unroll
    for (int tt = 0; tt < 2; ++tt) {
#pragma unroll
        for (int r = 0; r < 4; ++r) {
            size_t row = (size_t)(b * 1024 + qbase + tt * 16 + quad * 4 + r) * En;
#pragma unroll
            for (int dt = 0; dt < 4; ++dt)
                Po[row + h * 64 + dt * 16 + cl] = f2bf(acc[tt][dt][r]);
        }
    }
    if (quad == 0) {
#pragma unroll
        for (int tt = 0; tt < 2; ++tt)
            Lp[bh * 1024 + qbase + tt * 16 + cl] = l[tt];
    }
}

// ---------- K3: combine + out-proj + FUSED boundary-MLP ----------
__global__ __launch_bounds__(256) void k_out(const unsigned short* __restrict__ Po0,
                                             const unsigned short* __restrict__ Po1,
                                             const float* __restrict__ L0,
                                             const float* __restrict__ L1,
                                             const unsigned short* __restrict__ Wb,
                                             const float* __restrict__ bias,
                                             const unsigned short* __restrict__ w1h,
                                             const unsigned short* __restrict__ w1l,
                                             const float* __restrict__ b1,
                                             const float* __restrict__ w2,
                                             const float* __restrict__ b2,
                                             float* __restrict__ AO,
                                             float* __restrict__ bsc) {
    __shared__ unsigned short As[64][32];
    __shared__ unsigned short Bs[256][32];
    __shared__ unsigned short Ah[64][258];        // full-width bf16 AO rows
    int tid = threadIdx.x;
    int wv = tid >> 6, lane = tid & 63;
    int cl = lane & 15, quad = lane >> 4;
    size_t m0 = (size_t)blockIdx.x * 64;

    f32x4 acc[4][4];
#pragma unroll
    for (int mt = 0; mt < 4; ++mt)
#pragma unroll
        for (int nt = 0; nt < 4; ++nt) acc[mt][nt] = {0.f, 0.f, 0.f, 0.f};

    for (int kt = 0; kt < 8; ++kt) {
        if (kt) __syncthreads();
        {
            int row = tid >> 2, c4 = tid & 3;
            size_t g = (m0 + row) * En + kt * 32 + c4 * 8;
            uint4 u0 = *(const uint4*)(Po0 + g);
            uint4 u1 = *(const uint4*)(Po1 + g);
            int gt = (int)(m0 + row);
            int li = ((gt >> 10) * 4 + (kt >> 1)) * 1024 + (gt & 1023);
            float linv = 1.f / (L0[li] + L1[li]);
            unsigned int a0[4] = {u0.x, u0.y, u0.z, u0.w};
            unsigned int a1[4] = {u1.x, u1.y, u1.z, u1.w};
            unsigned int w[4];
#pragma unroll
            for (int j = 0; j < 4; ++j) {
                float lo = (bf2f((unsigned short)(a0[j] & 0xffff)) +
                            bf2f((unsigned short)(a1[j] & 0xffff))) * linv;
                float hi = (bf2f((unsigned short)(a0[j] >> 16)) +
                            bf2f((unsigned short)(a1[j] >> 16))) * linv;
                w[j] = f2bf(lo) | ((unsigned int)f2bf(hi) << 16);
            }
            *(uint4*)&As[row][c4 * 8] = make_uint4(w[0], w[1], w[2], w[3]);
        }
#pragma unroll
        for (int j = 0; j < 4; ++j) {
            int lin = j * 256 + tid; int n = lin >> 2, c = lin & 3;
            *(uint4*)&Bs[n][c * 8] =
                *(const uint4*)(Wb + (size_t)n * En + kt * 32 + c * 8);
        }
        __syncthreads();
        bf16x8 af[4], bfr[4];
#pragma unroll
        for (int mt = 0; mt < 4; ++mt)
            af[mt] = *(const bf16x8*)&As[mt * 16 + cl][quad * 8];
#pragma unroll
        for (int nt = 0; nt < 4; ++nt)
            bfr[nt] = *(const bf16x8*)&Bs[wv * 64 + nt * 16 + cl][quad * 8];
#pragma unroll
        for (int mt = 0; mt < 4; ++mt)
#pragma unroll
            for (int nt = 0; nt < 4; ++nt)
                acc[mt][nt] = __builtin_amdgcn_mfma_f32_16x16x32_bf16(af[mt], bfr[nt], acc[mt][nt], 0, 0, 0);
    }
    float bv[4];
#pragma unroll
    for (int nt = 0; nt < 4; ++nt) bv[nt] = bias[wv * 64 + nt * 16 + cl];
    __syncthreads();                               // As/Bs done; Ah phase begins
#pragma unroll
    for (int mt = 0; mt < 4; ++mt)
#pragma unroll
        for (int nt = 0; nt < 4; ++nt)
#pragma unroll
            for (int r = 0; r < 4; ++r) {
                float a = acc[mt][nt][r] + bv[nt];
                AO[(m0 + mt * 16 + quad * 4 + r) * En + wv * 64 + nt * 16 + cl] = a;
                Ah[mt * 16 + quad * 4 + r][wv * 64 + nt * 16 + cl] = f2bf(a);
            }
    __syncthreads();
    // boundary MLP: h1 = Ah @ w1^T (2 MFMAs: hi + lo), relu, *w2, sigmoid
    {
        f32x4 hacc[2] = {{0.f, 0.f, 0.f, 0.f}, {0.f, 0.f, 0.f, 0.f}};
        for (int kt = 0; kt < 8; ++kt) {
            bf16x8 ah = *(const bf16x8*)&Ah[wv * 16 + cl][kt * 32 + quad * 8];
#pragma unroll
            for (int nt = 0; nt < 2; ++nt) {
                size_t off = (size_t)(nt * 16 + cl) * En + kt * 32 + quad * 8;
                bf16x8 bh_ = *(const bf16x8*)(w1h + off);
                bf16x8 bl_ = *(const bf16x8*)(w1l + off);
                hacc[nt] = __builtin_amdgcn_mfma_f32_16x16x32_bf16(ah, bh_, hacc[nt], 0, 0, 0);
                hacc[nt] = __builtin_amdgcn_mfma_f32_16x16x32_bf16(ah, bl_, hacc[nt], 0, 0, 0);
            }
        }
        float b1v[2] = {b1[cl], b1[16 + cl]};
        float w2v[2] = {w2[cl], w2[16 + cl]};
        float b2v = b2[0];
        f32x4 z;
#pragma unroll
        for (int r = 0; r < 4; ++r)
            z[r] = fmaxf(hacc[0][r] + b1v[0], 0.f) * w2v[0] +
                   fmaxf(hacc[1][r] + b1v[1], 0.f) * w2v[1];
#pragma unroll
        for (int d = 1; d < 16; d <<= 1)
#pragma unroll
            for (int r = 0; r < 4; ++r) z[r] += __shfl_xor(z[r], d);
        if (cl == 0) {
#pragma unroll
            for (int r = 0; r < 4; ++r)
                bsc[m0 + wv * 16 + quad * 4 + r] =
                    1.f / (1.f + __expf(-(z[r] + b2v)));
        }
    }
}

// ---------- K4: pool with FUSED in-block scan (redundant per block, cheap) --
__global__ __launch_bounds__(256) void k_pool(const float* __restrict__ bsc,
                                              const float* __restrict__ AO,
                                              float* __restrict__ PE) {
    __shared__ float pre[1024];
    __shared__ float wsl[4];
    __shared__ float stot_s;
    __shared__ int   segs[33];
    int b = blockIdx.y, p = blockIdx.x, t = threadIdx.x;
    int lane = t & 63, wv = t >> 6;
    float4 v = *(const float4*)(bsc + b * 1024 + t * 4);
    float s0 = v.x, s1 = s0 + v.y, s2 = s1 + v.z, s3 = s2 + v.w;
    float ts = s3, sc = ts;
#pragma unroll
    for (int d = 1; d < 64; d <<= 1) {
        float y = __shfl_up(sc, d);
        if (lane >= d) sc += y;
    }
    if (lane == 63) wsl[wv] = sc;
    __syncthreads();
    if (t == 0) {
        float s = 0.f;
        for (int i = 0; i < 4; ++i) { float tmp = wsl[i]; wsl[i] = s; s += tmp; }
        stot_s = s;
    }
    __syncthreads();
    float base = wsl[wv] + (sc - ts);
    pre[t * 4 + 0] = base + s0;
    pre[t * 4 + 1] = base + s1;
    pre[t * 4 + 2] = base + s2;
    pre[t * 4 + 3] = base + s3;
    __syncthreads();
    float denom = stot_s + 1e-6f;
    int lastpid = 0;
#pragma unroll
    for (int i = 0; i < 4; ++i) {
        int t4 = t * 4 + i;
        int pid = min((int)floorf(pre[t4] / denom * 32.0f), 31);
        int pidprev = (t4 == 0) ? -1
                      : min((int)floorf(pre[t4 - 1] / denom * 32.0f), 31);
        for (int pp = pidprev + 1; pp <= pid; ++pp) segs[pp] = t4;
        lastpid = pid;
    }
    if (t == 255)
        for (int pp = lastpid + 1; pp <= 32; ++pp) segs[pp] = Tn;
    __syncthreads();
    int s = segs[p], e = segs[p + 1];
    float sum = 0.f;
    for (int tk = s; tk < e; ++tk)
        sum += AO[((size_t)b * Tn + tk) * En + t];
    PE[(size_t)(b * Pn + p) * En + t] = sum / fmaxf((float)(e - s), 1.f);
}

// ---------- K5: out = PE @ prw^T + prb  (hi/lo-split bf16 MFMA) ----------
__global__ __launch_bounds__(256) void k_final(const float* __restrict__ PE,
                                               const unsigned short* __restrict__ pwh,
                                               const unsigned short* __restrict__ pwl,
                                               const float* __restrict__ prb,
                                               float* __restrict__ out) {
    __shared__ unsigned short Ahs[64][40];
    __shared__ unsigned short Als[64][40];
    int tid = threadIdx.x;
    int wv = tid >> 6, lane = tid & 63;
    int cl = lane & 15, quad = lane >> 4;
    int m0 = blockIdx.x * 64;

    f32x4 acc[4][4];
#pragma unroll
    for (int mt = 0; mt < 4; ++mt)
#pragma unroll
        for (int nt = 0; nt < 4; ++nt) acc[mt][nt] = {0.f, 0.f, 0.f, 0.f};

    for (int kt = 0; kt < 8; ++kt) {
        if (kt) __syncthreads();
        {
            int row = tid >> 2, c8 = (tid & 3) * 8;
            const float* src = PE + (size_t)(m0 + row) * En + kt * 32 + c8;
            float4 a = *(const float4*)src, b4 = *(const float4*)(src + 4);
            float v[8] = {a.x, a.y, a.z, a.w, b4.x, b4.y, b4.z, b4.w};
            unsigned int hw[4], lw[4];
#pragma unroll
            for (int j = 0; j < 4; ++j) {
                unsigned short h0 = f2bf(v[2 * j]), h1 = f2bf(v[2 * j + 1]);
                unsigned short q0 = f2bf(v[2 * j] - bf2f(h0));
                unsigned short q1 = f2bf(v[2 * j + 1] - bf2f(h1));
                hw[j] = h0 | ((unsigned int)h1 << 16);
                lw[j] = q0 | ((unsigned int)q1 << 16);
            }
            *(uint4*)&Ahs[row][c8] = make_uint4(hw[0], hw[1], hw[2], hw[3]);
            *(uint4*)&Als[row][c8] = make_uint4(lw[0], lw[1], lw[2], lw[3]);
        }
        __syncthreads();
        bf16x8 ah[4], al[4], bh_[4], bl_[4];
#pragma unroll
        for (int mt = 0; mt < 4; ++mt) {
            ah[mt] = *(const bf16x8*)&Ahs[mt * 16 + cl][quad * 8];
            al[mt] = *(const bf16x8*)&Als[mt * 16 + cl][quad * 8];
        }
#pragma unroll
        for (int nt = 0; nt < 4; ++nt) {
            size_t off = (size_t)(wv * 64 + nt * 16 + cl) * En + kt * 32 + quad * 8;
            bh_[nt] = *(const bf16x8*)(pwh + off);
            bl_[nt] = *(const bf16x8*)(pwl + off);
        }
#pragma unroll
        for (int mt = 0; mt < 4; ++mt)
#pragma unroll
            for (int nt = 0; nt < 4; ++nt) {
                acc[mt][nt] = __builtin_amdgcn_mfma_f32_16x16x32_bf16(ah[mt], bh_[nt], acc[mt][nt], 0, 0, 0);
                acc[mt][nt] = __builtin_amdgcn_mfma_f32_16x16x32_bf16(ah[mt], bl_[nt], acc[mt][nt], 0, 0, 0);
                acc[mt][nt] = __builtin_amdgcn_mfma_f32_16x16x32_bf16(al[mt], bh_[nt], acc[mt][nt], 0, 0, 0);
            }
    }
    float bv[4];
#pragma unroll
    for (int nt = 0; nt < 4; ++nt) bv[nt] = prb[wv * 64 + nt * 16 + cl];
#pragma unroll
    for (int mt = 0; mt < 4; ++mt)
#pragma unroll
        for (int nt = 0; nt < 4; ++nt)
#pragma unroll
            for (int r = 0; r < 4; ++r)
                out[(size_t)(m0 + mt * 16 + quad * 4 + r) * En + wv * 64 + nt * 16 + cl] =
                    acc[mt][nt][r] + bv[nt];
}

extern "C" void kernel_launch(void* const* d_in, const int* in_sizes, int n_in,
                              void* d_out, int out_size, void* d_ws, size_t ws_size,
                              hipStream_t stream) {
    const float* x    = (const float*)d_in[0];
    const float* ipw  = (const float*)d_in[1];
    const float* ipb  = (const float*)d_in[2];
    const float* inw  = (const float*)d_in[3];
    const float* inb  = (const float*)d_in[4];
    const float* outw = (const float*)d_in[5];
    const float* outb = (const float*)d_in[6];
    const float* bw1  = (const float*)d_in[7];
    const float* bb1  = (const float*)d_in[8];
    const float* bw2  = (const float*)d_in[9];
    const float* bb2  = (const float*)d_in[10];
    const float* prw  = (const float*)d_in[11];
    const float* prb  = (const float*)d_in[12];

    char* base = (char*)d_ws;
    unsigned short* Qb  = (unsigned short*)base;
    unsigned short* Kb  = Qb + (size_t)8388608;
    float*          AO  = (float*)base;                                 // over Qb+Kb after attn
    unsigned short* Vt  = (unsigned short*)(base + (size_t)33554432);
    float*          PE  = (float*)(base + (size_t)33554432);            // over Vt after attn
    unsigned short* Po0 = (unsigned short*)(base + (size_t)50331648);
    unsigned short* Po1 = (unsigned short*)(base + (size_t)67108864);
    unsigned short* Wcb = (unsigned short*)(base + (size_t)83886080);   // 48 KB
    float*          bc  = (float*)(base + (size_t)83935232);            // 3 KB
    unsigned short* Wb  = (unsigned short*)(base + (size_t)83938304);   // 128 KB
    unsigned short* w1h = (unsigned short*)(base + (size_t)84069376);   // 16 KB
    unsigned short* w1l = (unsigned short*)(base + (size_t)84085760);   // 16 KB
    float*          L0  = (float*)(base + (size_t)84102144);            // 512 KB
    float*          L1  = (float*)(base + (size_t)84626432);            // 512 KB
    float*          bsc = (float*)(base + (size_t)85150720);            // 128 KB
    unsigned short* pwh = (unsigned short*)(base + (size_t)85286912);   // 128 KB
    unsigned short* pwl = (unsigned short*)(base + (size_t)85417984);   // 128 KB

    k_prep<<<99, 256, 0, stream>>>(ipw, ipb, inw, inb, Wcb, bc);
    k_qkv<<<864, 256, 0, stream>>>(x, Wcb, bc, outw, bw1, prw,
                                   Qb, Kb, Vt, Wb, w1h, w1l, pwh, pwl);
    k_attn<<<2048, 256, 0, stream>>>(Qb, Kb, Vt, Po0, Po1, L0, L1);
    k_out<<<512, 256, 0, stream>>>(Po0, Po1, L0, L1, Wb, outb,
                                   w1h, w1l, bb1, bw2, bb2, AO, bsc);
    k_pool<<<dim3(32, 32), 256, 0, stream>>>(bsc, AO, PE);
    k_final<<<16, 256, 0, stream>>>(PE, pwh, pwl, prb, (float*)d_out);
}

// Round 13
// 205.427 us; speedup vs baseline: 2.0753x; 1.0062x over previous
//
#include <hip/hip_runtime.h>
#include <math.h>

constexpr int Bn  = 32;
constexpr int Tn  = 1024;
constexpr int INn = 32;
constexpr int En  = 256;
constexpr int Pn  = 32;

typedef short bf16x8 __attribute__((ext_vector_type(8)));
typedef float f32x4  __attribute__((ext_vector_type(4)));

__device__ __forceinline__ unsigned short f2bf(float f) {
    unsigned int b = __float_as_uint(f);
    b += 0x7FFF + ((b >> 16) & 1);          // RNE
    return (unsigned short)(b >> 16);
}
__device__ __forceinline__ float bf2f(unsigned short h) {
    return __uint_as_float(((unsigned int)h) << 16);
}
// pack trunc-bf16(lo), trunc-bf16(hi) in ONE v_perm (bytes [2,3] of each)
__device__ __forceinline__ unsigned int permpack(float lo, float hi) {
    return __builtin_amdgcn_perm(__float_as_uint(hi), __float_as_uint(lo),
                                 0x07060302u);
}

// ---------- K0: prep — Wcb bf16 = in_proj_w @ ip_w, bc ----------
__global__ __launch_bounds__(256) void k_prep(const float* __restrict__ ipw,
                                              const float* __restrict__ ipb,
                                              const float* __restrict__ inw,
                                              const float* __restrict__ inb,
                                              unsigned short* __restrict__ Wcb,
                                              float* __restrict__ bc) {
    int blk = blockIdx.x, tid = threadIdx.x;
    if (blk < 96) {
        int idx = blk * 256 + tid;
        int o = idx >> 5, i = idx & 31;
        const float* wr = inw + (size_t)o * En;
        float a0 = 0.f, a1 = 0.f;
        for (int e = 0; e < En; e += 2) {
            a0 += wr[e]     * ipw[(size_t)e * INn + i];
            a1 += wr[e + 1] * ipw[(size_t)(e + 1) * INn + i];
        }
        Wcb[(size_t)o * INn + i] = f2bf(a0 + a1);
    } else {
        int o = (blk - 96) * 256 + tid;
        const float* wr = inw + (size_t)o * En;
        float a = inb[o];
        for (int e = 0; e < En; ++e) a += wr[e] * ipb[e];
        bc[o] = a;
    }
}

// ---------- K1: qkv projection (0..511) + weight conversions (512..863) ----
__global__ __launch_bounds__(256, 2) void k_qkv(const float* __restrict__ x,
                                                const unsigned short* __restrict__ Wcb,
                                                const float* __restrict__ bc,
                                                const float* __restrict__ outw,
                                                const float* __restrict__ w1,
                                                const float* __restrict__ prw,
                                                unsigned short* __restrict__ Qb,
                                                unsigned short* __restrict__ Kb,
                                                unsigned short* __restrict__ Vt,
                                                unsigned short* __restrict__ Wb,
                                                unsigned short* __restrict__ w1h,
                                                unsigned short* __restrict__ w1l,
                                                unsigned short* __restrict__ pwh,
                                                unsigned short* __restrict__ pwl) {
    int tid = threadIdx.x;
    if (blockIdx.x >= 512) {
        int cb = blockIdx.x - 512;
        if (cb < 64) {
            int idx = cb * 256 + tid;              // 16384 float4s
            float4 a = *(const float4*)(outw + (size_t)idx * 4);
            unsigned int u0 = f2bf(a.x) | ((unsigned int)f2bf(a.y) << 16);
            unsigned int u1 = f2bf(a.z) | ((unsigned int)f2bf(a.w) << 16);
            *(uint2*)(Wb + (size_t)idx * 4) = make_uint2(u0, u1);
        } else if (cb < 96) {
            int idx = (cb - 64) * 256 + tid;       // 8192 elements
            float a = w1[idx];
            unsigned short h = f2bf(a);
            w1h[idx] = h;
            w1l[idx] = f2bf(a - bf2f(h));
        } else {
            int idx = (cb - 96) * 256 + tid;       // 65536 elements
            float a = prw[idx];
            unsigned short h = f2bf(a);
            pwh[idx] = h;
            pwl[idx] = f2bf(a - bf2f(h));
        }
        return;
    }
    int wv = tid >> 6, lane = tid & 63;
    int cl = lane & 15, quad = lane >> 4;
    int m0 = blockIdx.x * 64;
    int b = m0 >> 10, tl0 = m0 & 1023;
    int n0w = wv * 192;
    f32x4 zero4 = {0.f, 0.f, 0.f, 0.f};

    bf16x8 wfrag[12]; float bv[12];
#pragma unroll
    for (int nt = 0; nt < 12; ++nt) {
        int col = n0w + nt * 16 + cl;
        wfrag[nt] = *(const bf16x8*)(Wcb + (size_t)col * 32 + quad * 8);
        bv[nt] = bc[col];
    }
#pragma unroll
    for (int mt = 0; mt < 4; ++mt) {
        const float* xr = x + (size_t)(m0 + mt * 16 + cl) * 32 + quad * 8;
        float4 xa = *(const float4*)xr, xc = *(const float4*)(xr + 4);
        bf16x8 af;
        af[0] = (short)f2bf(xa.x); af[1] = (short)f2bf(xa.y);
        af[2] = (short)f2bf(xa.z); af[3] = (short)f2bf(xa.w);
        af[4] = (short)f2bf(xc.x); af[5] = (short)f2bf(xc.y);
        af[6] = (short)f2bf(xc.z); af[7] = (short)f2bf(xc.w);
        f32x4 acc[12];
#pragma unroll
        for (int nt = 0; nt < 12; ++nt)
            acc[nt] = __builtin_amdgcn_mfma_f32_16x16x32_bf16(af, wfrag[nt], zero4, 0, 0, 0);
        int tloc = tl0 + mt * 16 + quad * 4;
#pragma unroll
        for (int nt = 0; nt < 12; ++nt) {
            int col = n0w + nt * 16 + cl;
            int slot = col >> 8, c = col & 255;
            int h = c >> 6, d = c & 63;
            int bh = b * 4 + h;
            if (slot == 2) {
                unsigned int u0 = f2bf(acc[nt][0] + bv[nt]) |
                                  ((unsigned int)f2bf(acc[nt][1] + bv[nt]) << 16);
                unsigned int u1 = f2bf(acc[nt][2] + bv[nt]) |
                                  ((unsigned int)f2bf(acc[nt][3] + bv[nt]) << 16);
                *(uint2*)(Vt + ((size_t)bh * 64 + d) * 1024 + tloc) = make_uint2(u0, u1);
            } else {
                unsigned short* dst = (slot ? Kb : Qb) +
                                      ((size_t)bh * 1024 + tloc) * 64 + d;
#pragma unroll
                for (int r = 0; r < 4; ++r)
                    dst[(size_t)r * 64] = f2bf(acc[nt][r] + bv[nt]);
            }
        }
    }
}

// ---------- K2: MFMA flash attention — 32q/wave, block K-split ----------
// grid 2048: bh = blk & 127, qb = (blk>>7)&7, half = blk>>10.  VGPR ~60.
// NOTE: __expf ONLY — libm exp2f costs +10 µs in guarded VALU ops (R10 A/B).
__global__ __launch_bounds__(256, 4) void k_attn(const unsigned short* __restrict__ Qb,
                                                 const unsigned short* __restrict__ Kb,
                                                 const unsigned short* __restrict__ Vt,
                                                 unsigned short* __restrict__ Po0,
                                                 unsigned short* __restrict__ Po1,
                                                 float* __restrict__ L0,
                                                 float* __restrict__ L1) {
    __shared__ unsigned short Ks[64][72];
    __shared__ unsigned short Vs[64][72];
    __shared__ __align__(16) unsigned short Pl[4][2][16][40];
    int blk = blockIdx.x;
    int bh = blk & 127;
    int r_ = blk >> 7;
    int qb = r_ & 7, half = r_ >> 3;
    int b = bh >> 2, h = bh & 3;
    int tid = threadIdx.x;
    int wv = tid >> 6, lane = tid & 63;
    int cl = lane & 15, quad = lane >> 4;
    int qbase = qb * 128 + wv * 32;

    f32x4 zero4 = {0.f, 0.f, 0.f, 0.f};
    bf16x8 qfrag[2][2];
#pragma unroll
    for (int tt = 0; tt < 2; ++tt)
#pragma unroll
        for (int ch = 0; ch < 2; ++ch)
            qfrag[tt][ch] = *(const bf16x8*)(Qb +
                ((size_t)bh * 1024 + qbase + tt * 16 + cl) * 64 + ch * 32 + quad * 8);
    f32x4 acc[2][4];
#pragma unroll
    for (int tt = 0; tt < 2; ++tt)
#pragma unroll
        for (int dt = 0; dt < 4; ++dt) acc[tt][dt] = zero4;
    float l[2] = {0.f, 0.f};

    const unsigned short* Kbase = Kb + (size_t)bh * 65536;
    const unsigned short* Vbase = Vt + (size_t)bh * 65536;

    for (int kt = 0; kt < 8; ++kt) {
        int ktt = half * 8 + kt;
#pragma unroll
        for (int r = 0; r < 2; ++r) {
            int idx = r * 256 + tid; int row = idx >> 3, c16 = idx & 7;
            *(uint4*)&Ks[row][c16 * 8] =
                *(const uint4*)(Kbase + (size_t)(ktt * 64 + row) * 64 + c16 * 8);
            *(uint4*)&Vs[row][c16 * 8] =
                *(const uint4*)(Vbase + (size_t)row * 1024 + ktt * 64 + c16 * 8);
        }
        __syncthreads();
#pragma unroll
        for (int c = 0; c < 2; ++c) {
            bf16x8 ka0 = *(const bf16x8*)&Ks[c * 32 + cl][quad * 8];
            bf16x8 ka1 = *(const bf16x8*)&Ks[c * 32 + cl][32 + quad * 8];
            bf16x8 kb0 = *(const bf16x8*)&Ks[c * 32 + 16 + cl][quad * 8];
            bf16x8 kb1 = *(const bf16x8*)&Ks[c * 32 + 16 + cl][32 + quad * 8];
            bf16x8 va[4];
#pragma unroll
            for (int dt = 0; dt < 4; ++dt)
                va[dt] = *(const bf16x8*)&Vs[dt * 16 + cl][c * 32 + quad * 8];
#pragma unroll
            for (int tt = 0; tt < 2; ++tt) {
                f32x4 s0 = __builtin_amdgcn_mfma_f32_16x16x32_bf16(ka0, qfrag[tt][0], zero4, 0, 0, 0);
                s0 = __builtin_amdgcn_mfma_f32_16x16x32_bf16(ka1, qfrag[tt][1], s0, 0, 0, 0);
                f32x4 s1 = __builtin_amdgcn_mfma_f32_16x16x32_bf16(kb0, qfrag[tt][0], zero4, 0, 0, 0);
                s1 = __builtin_amdgcn_mfma_f32_16x16x32_bf16(kb1, qfrag[tt][1], s1, 0, 0, 0);
                float p0 = __expf(0.125f * s0[0]), p1 = __expf(0.125f * s0[1]);
                float p2 = __expf(0.125f * s0[2]), p3 = __expf(0.125f * s0[3]);
                float p4 = __expf(0.125f * s1[0]), p5 = __expf(0.125f * s1[1]);
                float p6 = __expf(0.125f * s1[2]), p7 = __expf(0.125f * s1[3]);
                unsigned int w0 = permpack(p0, p1);
                unsigned int w1 = permpack(p2, p3);
                unsigned int w2 = permpack(p4, p5);
                unsigned int w3 = permpack(p6, p7);
                // l from the SAME truncated values -> bias cancels in o/l
                l[tt] += ((__uint_as_float(w0 << 16) + __uint_as_float(w0 & 0xffff0000u)) +
                          (__uint_as_float(w1 << 16) + __uint_as_float(w1 & 0xffff0000u))) +
                         ((__uint_as_float(w2 << 16) + __uint_as_float(w2 & 0xffff0000u)) +
                          (__uint_as_float(w3 << 16) + __uint_as_float(w3 & 0xffff0000u)));
                *(uint2*)&Pl[wv][tt][cl][quad * 4]      = make_uint2(w0, w1);
                *(uint2*)&Pl[wv][tt][cl][16 + quad * 4] = make_uint2(w2, w3);
            }
            asm volatile("s_waitcnt lgkmcnt(0)" ::: "memory");
#pragma unroll
            for (int tt = 0; tt < 2; ++tt) {
                bf16x8 pf = *(const bf16x8*)&Pl[wv][tt][cl][quad * 8];
#pragma unroll
                for (int dt = 0; dt < 4; ++dt)
                    acc[tt][dt] = __builtin_amdgcn_mfma_f32_16x16x32_bf16(pf, va[dt], acc[tt][dt], 0, 0, 0);
            }
        }
        __syncthreads();
    }
#pragma unroll
    for (int tt = 0; tt < 2; ++tt) {
        l[tt] += __shfl_xor(l[tt], 16);
        l[tt] += __shfl_xor(l[tt], 32);
    }
    unsigned short* Po = half ? Po1 : Po0;
    float* Lp = half ? L1 : L0;
#pragma unroll
    for (int tt = 0; tt < 2; ++tt) {
#pragma unroll
        for (int r = 0; r < 4; ++r) {
            size_t row = (size_t)(b * 1024 + qbase + tt * 16 + quad * 4 + r) * En;
#pragma unroll
            for (int dt = 0; dt < 4; ++dt)
                Po[row + h * 64 + dt * 16 + cl] = f2bf(acc[tt][dt][r]);
        }
    }
    if (quad == 0) {
#pragma unroll
        for (int tt = 0; tt < 2; ++tt)
            Lp[bh * 1024 + qbase + tt * 16 + cl] = l[tt];
    }
}

// ---------- K3: combine + out-proj + FUSED boundary-MLP; AO stored bf16 ----
__global__ __launch_bounds__(256) void k_out(const unsigned short* __restrict__ Po0,
                                             const unsigned short* __restrict__ Po1,
                                             const float* __restrict__ L0,
                                             const float* __restrict__ L1,
                                             const unsigned short* __restrict__ Wb,
                                             const float* __restrict__ bias,
                                             const unsigned short* __restrict__ w1h,
                                             const unsigned short* __restrict__ w1l,
                                             const float* __restrict__ b1,
                                             const float* __restrict__ w2,
                                             const float* __restrict__ b2,
                                             unsigned short* __restrict__ AOb,
                                             float* __restrict__ bsc) {
    __shared__ unsigned short As[64][32];
    __shared__ unsigned short Bs[256][32];
    __shared__ unsigned short Ah[64][258];        // full-width bf16 AO rows
    int tid = threadIdx.x;
    int wv = tid >> 6, lane = tid & 63;
    int cl = lane & 15, quad = lane >> 4;
    size_t m0 = (size_t)blockIdx.x * 64;

    f32x4 acc[4][4];
#pragma unroll
    for (int mt = 0; mt < 4; ++mt)
#pragma unroll
        for (int nt = 0; nt < 4; ++nt) acc[mt][nt] = {0.f, 0.f, 0.f, 0.f};

    for (int kt = 0; kt < 8; ++kt) {
        if (kt) __syncthreads();
        {
            int row = tid >> 2, c4 = tid & 3;
            size_t g = (m0 + row) * En + kt * 32 + c4 * 8;
            uint4 u0 = *(const uint4*)(Po0 + g);
            uint4 u1 = *(const uint4*)(Po1 + g);
            int gt = (int)(m0 + row);
            int li = ((gt >> 10) * 4 + (kt >> 1)) * 1024 + (gt & 1023);
            float linv = 1.f / (L0[li] + L1[li]);
            unsigned int a0[4] = {u0.x, u0.y, u0.z, u0.w};
            unsigned int a1[4] = {u1.x, u1.y, u1.z, u1.w};
            unsigned int w[4];
#pragma unroll
            for (int j = 0; j < 4; ++j) {
                float lo = (bf2f((unsigned short)(a0[j] & 0xffff)) +
                            bf2f((unsigned short)(a1[j] & 0xffff))) * linv;
                float hi = (bf2f((unsigned short)(a0[j] >> 16)) +
                            bf2f((unsigned short)(a1[j] >> 16))) * linv;
                w[j] = f2bf(lo) | ((unsigned int)f2bf(hi) << 16);
            }
            *(uint4*)&As[row][c4 * 8] = make_uint4(w[0], w[1], w[2], w[3]);
        }
#pragma unroll
        for (int j = 0; j < 4; ++j) {
            int lin = j * 256 + tid; int n = lin >> 2, c = lin & 3;
            *(uint4*)&Bs[n][c * 8] =
                *(const uint4*)(Wb + (size_t)n * En + kt * 32 + c * 8);
        }
        __syncthreads();
        bf16x8 af[4], bfr[4];
#pragma unroll
        for (int mt = 0; mt < 4; ++mt)
            af[mt] = *(const bf16x8*)&As[mt * 16 + cl][quad * 8];
#pragma unroll
        for (int nt = 0; nt < 4; ++nt)
            bfr[nt] = *(const bf16x8*)&Bs[wv * 64 + nt * 16 + cl][quad * 8];
#pragma unroll
        for (int mt = 0; mt < 4; ++mt)
#pragma unroll
            for (int nt = 0; nt < 4; ++nt)
                acc[mt][nt] = __builtin_amdgcn_mfma_f32_16x16x32_bf16(af[mt], bfr[nt], acc[mt][nt], 0, 0, 0);
    }
    float bv[4];
#pragma unroll
    for (int nt = 0; nt < 4; ++nt) bv[nt] = bias[wv * 64 + nt * 16 + cl];
    __syncthreads();                               // As/Bs done; Ah phase begins
#pragma unroll
    for (int mt = 0; mt < 4; ++mt)
#pragma unroll
        for (int nt = 0; nt < 4; ++nt)
#pragma unroll
            for (int r = 0; r < 4; ++r) {
                float a = acc[mt][nt][r] + bv[nt];
                unsigned short ab = f2bf(a);
                AOb[(m0 + mt * 16 + quad * 4 + r) * En + wv * 64 + nt * 16 + cl] = ab;
                Ah[mt * 16 + quad * 4 + r][wv * 64 + nt * 16 + cl] = ab;
            }
    __syncthreads();
    // boundary MLP: h1 = Ah @ w1^T (2 MFMAs: hi + lo), relu, *w2, sigmoid
    {
        f32x4 hacc[2] = {{0.f, 0.f, 0.f, 0.f}, {0.f, 0.f, 0.f, 0.f}};
        for (int kt = 0; kt < 8; ++kt) {
            bf16x8 ah = *(const bf16x8*)&Ah[wv * 16 + cl][kt * 32 + quad * 8];
#pragma unroll
            for (int nt = 0; nt < 2; ++nt) {
                size_t off = (size_t)(nt * 16 + cl) * En + kt * 32 + quad * 8;
                bf16x8 bh_ = *(const bf16x8*)(w1h + off);
                bf16x8 bl_ = *(const bf16x8*)(w1l + off);
                hacc[nt] = __builtin_amdgcn_mfma_f32_16x16x32_bf16(ah, bh_, hacc[nt], 0, 0, 0);
                hacc[nt] = __builtin_amdgcn_mfma_f32_16x16x32_bf16(ah, bl_, hacc[nt], 0, 0, 0);
            }
        }
        float b1v[2] = {b1[cl], b1[16 + cl]};
        float w2v[2] = {w2[cl], w2[16 + cl]};
        float b2v = b2[0];
        f32x4 z;
#pragma unroll
        for (int r = 0; r < 4; ++r)
            z[r] = fmaxf(hacc[0][r] + b1v[0], 0.f) * w2v[0] +
                   fmaxf(hacc[1][r] + b1v[1], 0.f) * w2v[1];
#pragma unroll
        for (int d = 1; d < 16; d <<= 1)
#pragma unroll
            for (int r = 0; r < 4; ++r) z[r] += __shfl_xor(z[r], d);
        if (cl == 0) {
#pragma unroll
            for (int r = 0; r < 4; ++r)
                bsc[m0 + wv * 16 + quad * 4 + r] =
                    1.f / (1.f + __expf(-(z[r] + b2v)));
        }
    }
}

// ---------- K4: pool with fused in-block scan; AO read as bf16 ----------
__global__ __launch_bounds__(256) void k_pool(const float* __restrict__ bsc,
                                              const unsigned short* __restrict__ AOb,
                                              float* __restrict__ PE) {
    __shared__ float pre[1024];
    __shared__ float wsl[4];
    __shared__ float stot_s;
    __shared__ int   segs[33];
    int b = blockIdx.y, p = blockIdx.x, t = threadIdx.x;
    int lane = t & 63, wv = t >> 6;
    float4 v = *(const float4*)(bsc + b * 1024 + t * 4);
    float s0 = v.x, s1 = s0 + v.y, s2 = s1 + v.z, s3 = s2 + v.w;
    float ts = s3, sc = ts;
#pragma unroll
    for (int d = 1; d < 64; d <<= 1) {
        float y = __shfl_up(sc, d);
        if (lane >= d) sc += y;
    }
    if (lane == 63) wsl[wv] = sc;
    __syncthreads();
    if (t == 0) {
        float s = 0.f;
        for (int i = 0; i < 4; ++i) { float tmp = wsl[i]; wsl[i] = s; s += tmp; }
        stot_s = s;
    }
    __syncthreads();
    float base = wsl[wv] + (sc - ts);
    pre[t * 4 + 0] = base + s0;
    pre[t * 4 + 1] = base + s1;
    pre[t * 4 + 2] = base + s2;
    pre[t * 4 + 3] = base + s3;
    __syncthreads();
    float denom = stot_s + 1e-6f;
    int lastpid = 0;
#pragma unroll
    for (int i = 0; i < 4; ++i) {
        int t4 = t * 4 + i;
        int pid = min((int)floorf(pre[t4] / denom * 32.0f), 31);
        int pidprev = (t4 == 0) ? -1
                      : min((int)floorf(pre[t4 - 1] / denom * 32.0f), 31);
        for (int pp = pidprev + 1; pp <= pid; ++pp) segs[pp] = t4;
        lastpid = pid;
    }
    if (t == 255)
        for (int pp = lastpid + 1; pp <= 32; ++pp) segs[pp] = Tn;
    __syncthreads();
    int s = segs[p], e = segs[p + 1];
    float sum = 0.f;
    for (int tk = s; tk < e; ++tk)
        sum += bf2f(AOb[((size_t)b * Tn + tk) * En + t]);
    PE[(size_t)(b * Pn + p) * En + t] = sum / fmaxf((float)(e - s), 1.f);
}

// ---------- K5: out = PE @ prw^T + prb  (hi/lo-split bf16 MFMA) ----------
__global__ __launch_bounds__(256) void k_final(const float* __restrict__ PE,
                                               const unsigned short* __restrict__ pwh,
                                               const unsigned short* __restrict__ pwl,
                                               const float* __restrict__ prb,
                                               float* __restrict__ out) {
    __shared__ unsigned short Ahs[64][40];
    __shared__ unsigned short Als[64][40];
    int tid = threadIdx.x;
    int wv = tid >> 6, lane = tid & 63;
    int cl = lane & 15, quad = lane >> 4;
    int m0 = blockIdx.x * 64;

    f32x4 acc[4][4];
#pragma unroll
    for (int mt = 0; mt < 4; ++mt)
#pragma unroll
        for (int nt = 0; nt < 4; ++nt) acc[mt][nt] = {0.f, 0.f, 0.f, 0.f};

    for (int kt = 0; kt < 8; ++kt) {
        if (kt) __syncthreads();
        {
            int row = tid >> 2, c8 = (tid & 3) * 8;
            const float* src = PE + (size_t)(m0 + row) * En + kt * 32 + c8;
            float4 a = *(const float4*)src, b4 = *(const float4*)(src + 4);
            float v[8] = {a.x, a.y, a.z, a.w, b4.x, b4.y, b4.z, b4.w};
            unsigned int hw[4], lw[4];
#pragma unroll
            for (int j = 0; j < 4; ++j) {
                unsigned short h0 = f2bf(v[2 * j]), h1 = f2bf(v[2 * j + 1]);
                unsigned short q0 = f2bf(v[2 * j] - bf2f(h0));
                unsigned short q1 = f2bf(v[2 * j + 1] - bf2f(h1));
                hw[j] = h0 | ((unsigned int)h1 << 16);
                lw[j] = q0 | ((unsigned int)q1 << 16);
            }
            *(uint4*)&Ahs[row][c8] = make_uint4(hw[0], hw[1], hw[2], hw[3]);
            *(uint4*)&Als[row][c8] = make_uint4(lw[0], lw[1], lw[2], lw[3]);
        }
        __syncthreads();
        bf16x8 ah[4], al[4], bh_[4], bl_[4];
#pragma unroll
        for (int mt = 0; mt < 4; ++mt) {
            ah[mt] = *(const bf16x8*)&Ahs[mt * 16 + cl][quad * 8];
            al[mt] = *(const bf16x8*)&Als[mt * 16 + cl][quad * 8];
        }
#pragma unroll
        for (int nt = 0; nt < 4; ++nt) {
            size_t off = (size_t)(wv * 64 + nt * 16 + cl) * En + kt * 32 + quad * 8;
            bh_[nt] = *(const bf16x8*)(pwh + off);
            bl_[nt] = *(const bf16x8*)(pwl + off);
        }
#pragma unroll
        for (int mt = 0; mt < 4; ++mt)
#pragma unroll
            for (int nt = 0; nt < 4; ++nt) {
                acc[mt][nt] = __builtin_amdgcn_mfma_f32_16x16x32_bf16(ah[mt], bh_[nt], acc[mt][nt], 0, 0, 0);
                acc[mt][nt] = __builtin_amdgcn_mfma_f32_16x16x32_bf16(ah[mt], bl_[nt], acc[mt][nt], 0, 0, 0);
                acc[mt][nt] = __builtin_amdgcn_mfma_f32_16x16x32_bf16(al[mt], bh_[nt], acc[mt][nt], 0, 0, 0);
            }
    }
    float bv[4];
#pragma unroll
    for (int nt = 0; nt < 4; ++nt) bv[nt] = prb[wv * 64 + nt * 16 + cl];
#pragma unroll
    for (int mt = 0; mt < 4; ++mt)
#pragma unroll
        for (int nt = 0; nt < 4; ++nt)
#pragma unroll
            for (int r = 0; r < 4; ++r)
                out[(size_t)(m0 + mt * 16 + quad * 4 + r) * En + wv * 64 + nt * 16 + cl] =
                    acc[mt][nt][r] + bv[nt];
}

extern "C" void kernel_launch(void* const* d_in, const int* in_sizes, int n_in,
                              void* d_out, int out_size, void* d_ws, size_t ws_size,
                              hipStream_t stream) {
    const float* x    = (const float*)d_in[0];
    const float* ipw  = (const float*)d_in[1];
    const float* ipb  = (const float*)d_in[2];
    const float* inw  = (const float*)d_in[3];
    const float* inb  = (const float*)d_in[4];
    const float* outw = (const float*)d_in[5];
    const float* outb = (const float*)d_in[6];
    const float* bw1  = (const float*)d_in[7];
    const float* bb1  = (const float*)d_in[8];
    const float* bw2  = (const float*)d_in[9];
    const float* bb2  = (const float*)d_in[10];
    const float* prw  = (const float*)d_in[11];
    const float* prb  = (const float*)d_in[12];

    char* base = (char*)d_ws;
    unsigned short* Qb  = (unsigned short*)base;
    unsigned short* Kb  = Qb + (size_t)8388608;
    unsigned short* AOb = (unsigned short*)base;                        // over Qb (dead after attn)
    unsigned short* Vt  = (unsigned short*)(base + (size_t)33554432);
    float*          PE  = (float*)(base + (size_t)33554432);            // over Vt after attn
    unsigned short* Po0 = (unsigned short*)(base + (size_t)50331648);
    unsigned short* Po1 = (unsigned short*)(base + (size_t)67108864);
    unsigned short* Wcb = (unsigned short*)(base + (size_t)83886080);   // 48 KB
    float*          bc  = (float*)(base + (size_t)83935232);            // 3 KB
    unsigned short* Wb  = (unsigned short*)(base + (size_t)83938304);   // 128 KB
    unsigned short* w1h = (unsigned short*)(base + (size_t)84069376);   // 16 KB
    unsigned short* w1l = (unsigned short*)(base + (size_t)84085760);   // 16 KB
    float*          L0  = (float*)(base + (size_t)84102144);            // 512 KB
    float*          L1  = (float*)(base + (size_t)84626432);            // 512 KB
    float*          bsc = (float*)(base + (size_t)85150720);            // 128 KB
    unsigned short* pwh = (unsigned short*)(base + (size_t)85286912);   // 128 KB
    unsigned short* pwl = (unsigned short*)(base + (size_t)85417984);   // 128 KB

    k_prep<<<99, 256, 0, stream>>>(ipw, ipb, inw, inb, Wcb, bc);
    k_qkv<<<864, 256, 0, stream>>>(x, Wcb, bc, outw, bw1, prw,
                                   Qb, Kb, Vt, Wb, w1h, w1l, pwh, pwl);
    k_attn<<<2048, 256, 0, stream>>>(Qb, Kb, Vt, Po0, Po1, L0, L1);
    k_out<<<512, 256, 0, stream>>>(Po0, Po1, L0, L1, Wb, outb,
                                   w1h, w1l, bb1, bw2, bb2, AOb, bsc);
    k_pool<<<dim3(32, 32), 256, 0, stream>>>(bsc, AOb, PE);
    k_final<<<16, 256, 0, stream>>>(PE, pwh, pwl, prb, (float*)d_out);
}

// Round 14
// 198.194 us; speedup vs baseline: 2.1511x; 1.0365x over previous
//
#include <hip/hip_runtime.h>
#include <math.h>

constexpr int Bn  = 32;
constexpr int Tn  = 1024;
constexpr int INn = 32;
constexpr int En  = 256;
constexpr int Pn  = 32;

typedef short bf16x8 __attribute__((ext_vector_type(8)));
typedef float f32x4  __attribute__((ext_vector_type(4)));

__device__ __forceinline__ unsigned short f2bf(float f) {
    unsigned int b = __float_as_uint(f);
    b += 0x7FFF + ((b >> 16) & 1);          // RNE
    return (unsigned short)(b >> 16);
}
__device__ __forceinline__ float bf2f(unsigned short h) {
    return __uint_as_float(((unsigned int)h) << 16);
}
// pack trunc-bf16(lo), trunc-bf16(hi) in ONE v_perm (bytes [2,3] of each)
__device__ __forceinline__ unsigned int permpack(float lo, float hi) {
    return __builtin_amdgcn_perm(__float_as_uint(hi), __float_as_uint(lo),
                                 0x07060302u);
}

// ---------- K0: prep v2 — LDS-staged (latency fix: was serial global dots) --
// blocks [0,96): Wcb (8 o-rows each, ipw+inw in LDS)
// blocks [96,288): bc (wave-per-row, lane-parallel e, shuffle reduce)
__global__ __launch_bounds__(256) void k_prep(const float* __restrict__ ipw,
                                              const float* __restrict__ ipb,
                                              const float* __restrict__ inw,
                                              const float* __restrict__ inb,
                                              unsigned short* __restrict__ Wcb,
                                              float* __restrict__ bc) {
    int blk = blockIdx.x, tid = threadIdx.x;
    if (blk < 96) {
        __shared__ float ipw_s[256 * 32];          // 32 KB
        __shared__ float inw_s[8 * 256];           // 8 KB
        int o0 = blk * 8;
        float4* ipv = (float4*)ipw_s;
#pragma unroll
        for (int j = 0; j < 8; ++j)
            ipv[tid + j * 256] = ((const float4*)ipw)[tid + j * 256];
        float4* inv = (float4*)inw_s;
        const float4* src = (const float4*)(inw + (size_t)o0 * En);
#pragma unroll
        for (int j = 0; j < 2; ++j)
            inv[tid + j * 256] = src[tid + j * 256];
        __syncthreads();
        int oL = tid >> 5, i = tid & 31;
        float a0 = 0.f, a1 = 0.f;
#pragma unroll 4
        for (int e = 0; e < 256; e += 2) {
            a0 += inw_s[oL * 256 + e]     * ipw_s[e * 32 + i];
            a1 += inw_s[oL * 256 + e + 1] * ipw_s[(e + 1) * 32 + i];
        }
        Wcb[(size_t)(o0 + oL) * 32 + i] = f2bf(a0 + a1);
    } else {
        int c = blk - 96;
        int lane = tid & 63, wv = tid >> 6;
        int o = c * 4 + wv;                        // 0..767
        float4 w4 = *(const float4*)(inw + (size_t)o * En + lane * 4);
        float4 p4 = *(const float4*)(ipb + lane * 4);
        float a = w4.x * p4.x + w4.y * p4.y + w4.z * p4.z + w4.w * p4.w;
#pragma unroll
        for (int d = 1; d < 64; d <<= 1) a += __shfl_xor(a, d);
        if (lane == 0) bc[o] = a + inb[o];
    }
}

// ---------- K1: qkv projection (0..511) + weight conversions (512..863) ----
__global__ __launch_bounds__(256, 2) void k_qkv(const float* __restrict__ x,
                                                const unsigned short* __restrict__ Wcb,
                                                const float* __restrict__ bc,
                                                const float* __restrict__ outw,
                                                const float* __restrict__ w1,
                                                const float* __restrict__ prw,
                                                unsigned short* __restrict__ Qb,
                                                unsigned short* __restrict__ Kb,
                                                unsigned short* __restrict__ Vt,
                                                unsigned short* __restrict__ Wb,
                                                unsigned short* __restrict__ w1h,
                                                unsigned short* __restrict__ w1l,
                                                unsigned short* __restrict__ pwh,
                                                unsigned short* __restrict__ pwl) {
    int tid = threadIdx.x;
    if (blockIdx.x >= 512) {
        int cb = blockIdx.x - 512;
        if (cb < 64) {
            int idx = cb * 256 + tid;              // 16384 float4s
            float4 a = *(const float4*)(outw + (size_t)idx * 4);
            unsigned int u0 = f2bf(a.x) | ((unsigned int)f2bf(a.y) << 16);
            unsigned int u1 = f2bf(a.z) | ((unsigned int)f2bf(a.w) << 16);
            *(uint2*)(Wb + (size_t)idx * 4) = make_uint2(u0, u1);
        } else if (cb < 96) {
            int idx = (cb - 64) * 256 + tid;       // 8192 elements
            float a = w1[idx];
            unsigned short h = f2bf(a);
            w1h[idx] = h;
            w1l[idx] = f2bf(a - bf2f(h));
        } else {
            int idx = (cb - 96) * 256 + tid;       // 65536 elements
            float a = prw[idx];
            unsigned short h = f2bf(a);
            pwh[idx] = h;
            pwl[idx] = f2bf(a - bf2f(h));
        }
        return;
    }
    int wv = tid >> 6, lane = tid & 63;
    int cl = lane & 15, quad = lane >> 4;
    int m0 = blockIdx.x * 64;
    int b = m0 >> 10, tl0 = m0 & 1023;
    int n0w = wv * 192;
    f32x4 zero4 = {0.f, 0.f, 0.f, 0.f};

    bf16x8 wfrag[12]; float bv[12];
#pragma unroll
    for (int nt = 0; nt < 12; ++nt) {
        int col = n0w + nt * 16 + cl;
        wfrag[nt] = *(const bf16x8*)(Wcb + (size_t)col * 32 + quad * 8);
        bv[nt] = bc[col];
    }
#pragma unroll
    for (int mt = 0; mt < 4; ++mt) {
        const float* xr = x + (size_t)(m0 + mt * 16 + cl) * 32 + quad * 8;
        float4 xa = *(const float4*)xr, xc = *(const float4*)(xr + 4);
        bf16x8 af;
        af[0] = (short)f2bf(xa.x); af[1] = (short)f2bf(xa.y);
        af[2] = (short)f2bf(xa.z); af[3] = (short)f2bf(xa.w);
        af[4] = (short)f2bf(xc.x); af[5] = (short)f2bf(xc.y);
        af[6] = (short)f2bf(xc.z); af[7] = (short)f2bf(xc.w);
        f32x4 acc[12];
#pragma unroll
        for (int nt = 0; nt < 12; ++nt)
            acc[nt] = __builtin_amdgcn_mfma_f32_16x16x32_bf16(af, wfrag[nt], zero4, 0, 0, 0);
        int tloc = tl0 + mt * 16 + quad * 4;
#pragma unroll
        for (int nt = 0; nt < 12; ++nt) {
            int col = n0w + nt * 16 + cl;
            int slot = col >> 8, c = col & 255;
            int h = c >> 6, d = c & 63;
            int bh = b * 4 + h;
            if (slot == 2) {
                unsigned int u0 = f2bf(acc[nt][0] + bv[nt]) |
                                  ((unsigned int)f2bf(acc[nt][1] + bv[nt]) << 16);
                unsigned int u1 = f2bf(acc[nt][2] + bv[nt]) |
                                  ((unsigned int)f2bf(acc[nt][3] + bv[nt]) << 16);
                *(uint2*)(Vt + ((size_t)bh * 64 + d) * 1024 + tloc) = make_uint2(u0, u1);
            } else {
                unsigned short* dst = (slot ? Kb : Qb) +
                                      ((size_t)bh * 1024 + tloc) * 64 + d;
#pragma unroll
                for (int r = 0; r < 4; ++r)
                    dst[(size_t)r * 64] = f2bf(acc[nt][r] + bv[nt]);
            }
        }
    }
}

// ---------- K2: MFMA flash attention — 32q/wave, block K-split ----------
// grid 2048: bh = blk & 127, qb = (blk>>7)&7, half = blk>>10.  VGPR ~60.
// NOTE: __expf ONLY — libm exp2f costs +10 µs in guarded VALU ops (R10 A/B).
__global__ __launch_bounds__(256, 4) void k_attn(const unsigned short* __restrict__ Qb,
                                                 const unsigned short* __restrict__ Kb,
                                                 const unsigned short* __restrict__ Vt,
                                                 unsigned short* __restrict__ Po0,
                                                 unsigned short* __restrict__ Po1,
                                                 float* __restrict__ L0,
                                                 float* __restrict__ L1) {
    __shared__ unsigned short Ks[64][72];
    __shared__ unsigned short Vs[64][72];
    __shared__ __align__(16) unsigned short Pl[4][2][16][40];
    int blk = blockIdx.x;
    int bh = blk & 127;
    int r_ = blk >> 7;
    int qb = r_ & 7, half = r_ >> 3;
    int b = bh >> 2, h = bh & 3;
    int tid = threadIdx.x;
    int wv = tid >> 6, lane = tid & 63;
    int cl = lane & 15, quad = lane >> 4;
    int qbase = qb * 128 + wv * 32;

    f32x4 zero4 = {0.f, 0.f, 0.f, 0.f};
    bf16x8 qfrag[2][2];
#pragma unroll
    for (int tt = 0; tt < 2; ++tt)
#pragma unroll
        for (int ch = 0; ch < 2; ++ch)
            qfrag[tt][ch] = *(const bf16x8*)(Qb +
                ((size_t)bh * 1024 + qbase + tt * 16 + cl) * 64 + ch * 32 + quad * 8);
    f32x4 acc[2][4];
#pragma unroll
    for (int tt = 0; tt < 2; ++tt)
#pragma unroll
        for (int dt = 0; dt < 4; ++dt) acc[tt][dt] = zero4;
    float l[2] = {0.f, 0.f};

    const unsigned short* Kbase = Kb + (size_t)bh * 65536;
    const unsigned short* Vbase = Vt + (size_t)bh * 65536;

    for (int kt = 0; kt < 8; ++kt) {
        int ktt = half * 8 + kt;
#pragma unroll
        for (int r = 0; r < 2; ++r) {
            int idx = r * 256 + tid; int row = idx >> 3, c16 = idx & 7;
            *(uint4*)&Ks[row][c16 * 8] =
                *(const uint4*)(Kbase + (size_t)(ktt * 64 + row) * 64 + c16 * 8);
            *(uint4*)&Vs[row][c16 * 8] =
                *(const uint4*)(Vbase + (size_t)row * 1024 + ktt * 64 + c16 * 8);
        }
        __syncthreads();
#pragma unroll
        for (int c = 0; c < 2; ++c) {
            bf16x8 ka0 = *(const bf16x8*)&Ks[c * 32 + cl][quad * 8];
            bf16x8 ka1 = *(const bf16x8*)&Ks[c * 32 + cl][32 + quad * 8];
            bf16x8 kb0 = *(const bf16x8*)&Ks[c * 32 + 16 + cl][quad * 8];
            bf16x8 kb1 = *(const bf16x8*)&Ks[c * 32 + 16 + cl][32 + quad * 8];
            bf16x8 va[4];
#pragma unroll
            for (int dt = 0; dt < 4; ++dt)
                va[dt] = *(const bf16x8*)&Vs[dt * 16 + cl][c * 32 + quad * 8];
#pragma unroll
            for (int tt = 0; tt < 2; ++tt) {
                f32x4 s0 = __builtin_amdgcn_mfma_f32_16x16x32_bf16(ka0, qfrag[tt][0], zero4, 0, 0, 0);
                s0 = __builtin_amdgcn_mfma_f32_16x16x32_bf16(ka1, qfrag[tt][1], s0, 0, 0, 0);
                f32x4 s1 = __builtin_amdgcn_mfma_f32_16x16x32_bf16(kb0, qfrag[tt][0], zero4, 0, 0, 0);
                s1 = __builtin_amdgcn_mfma_f32_16x16x32_bf16(kb1, qfrag[tt][1], s1, 0, 0, 0);
                float p0 = __expf(0.125f * s0[0]), p1 = __expf(0.125f * s0[1]);
                float p2 = __expf(0.125f * s0[2]), p3 = __expf(0.125f * s0[3]);
                float p4 = __expf(0.125f * s1[0]), p5 = __expf(0.125f * s1[1]);
                float p6 = __expf(0.125f * s1[2]), p7 = __expf(0.125f * s1[3]);
                unsigned int w0 = permpack(p0, p1);
                unsigned int w1 = permpack(p2, p3);
                unsigned int w2 = permpack(p4, p5);
                unsigned int w3 = permpack(p6, p7);
                // l from the SAME truncated values -> bias cancels in o/l
                l[tt] += ((__uint_as_float(w0 << 16) + __uint_as_float(w0 & 0xffff0000u)) +
                          (__uint_as_float(w1 << 16) + __uint_as_float(w1 & 0xffff0000u))) +
                         ((__uint_as_float(w2 << 16) + __uint_as_float(w2 & 0xffff0000u)) +
                          (__uint_as_float(w3 << 16) + __uint_as_float(w3 & 0xffff0000u)));
                *(uint2*)&Pl[wv][tt][cl][quad * 4]      = make_uint2(w0, w1);
                *(uint2*)&Pl[wv][tt][cl][16 + quad * 4] = make_uint2(w2, w3);
            }
            asm volatile("s_waitcnt lgkmcnt(0)" ::: "memory");
#pragma unroll
            for (int tt = 0; tt < 2; ++tt) {
                bf16x8 pf = *(const bf16x8*)&Pl[wv][tt][cl][quad * 8];
#pragma unroll
                for (int dt = 0; dt < 4; ++dt)
                    acc[tt][dt] = __builtin_amdgcn_mfma_f32_16x16x32_bf16(pf, va[dt], acc[tt][dt], 0, 0, 0);
            }
        }
        __syncthreads();
    }
#pragma unroll
    for (int tt = 0; tt < 2; ++tt) {
        l[tt] += __shfl_xor(l[tt], 16);
        l[tt] += __shfl_xor(l[tt], 32);
    }
    unsigned short* Po = half ? Po1 : Po0;
    float* Lp = half ? L1 : L0;
#pragma unroll
    for (int tt = 0; tt < 2; ++tt) {
#pragma unroll
        for (int r = 0; r < 4; ++r) {
            size_t row = (size_t)(b * 1024 + qbase + tt * 16 + quad * 4 + r) * En;
#pragma unroll
            for (int dt = 0; dt < 4; ++dt)
                Po[row + h * 64 + dt * 16 + cl] = f2bf(acc[tt][dt][r]);
        }
    }
    if (quad == 0) {
#pragma unroll
        for (int tt = 0; tt < 2; ++tt)
            Lp[bh * 1024 + qbase + tt * 16 + cl] = l[tt];
    }
}

// ---------- K3: combine + out-proj + FUSED boundary-MLP; AO stored bf16 ----
__global__ __launch_bounds__(256) void k_out(const unsigned short* __restrict__ Po0,
                                             const unsigned short* __restrict__ Po1,
                                             const float* __restrict__ L0,
                                             const float* __restrict__ L1,
                                             const unsigned short* __restrict__ Wb,
                                             const float* __restrict__ bias,
                                             const unsigned short* __restrict__ w1h,
                                             const unsigned short* __restrict__ w1l,
                                             const float* __restrict__ b1,
                                             const float* __restrict__ w2,
                                             const float* __restrict__ b2,
                                             unsigned short* __restrict__ AOb,
                                             float* __restrict__ bsc) {
    __shared__ unsigned short As[64][32];
    __shared__ unsigned short Bs[256][32];
    __shared__ unsigned short Ah[64][258];        // full-width bf16 AO rows
    int tid = threadIdx.x;
    int wv = tid >> 6, lane = tid & 63;
    int cl = lane & 15, quad = lane >> 4;
    size_t m0 = (size_t)blockIdx.x * 64;

    f32x4 acc[4][4];
#pragma unroll
    for (int mt = 0; mt < 4; ++mt)
#pragma unroll
        for (int nt = 0; nt < 4; ++nt) acc[mt][nt] = {0.f, 0.f, 0.f, 0.f};

    for (int kt = 0; kt < 8; ++kt) {
        if (kt) __syncthreads();
        {
            int row = tid >> 2, c4 = tid & 3;
            size_t g = (m0 + row) * En + kt * 32 + c4 * 8;
            uint4 u0 = *(const uint4*)(Po0 + g);
            uint4 u1 = *(const uint4*)(Po1 + g);
            int gt = (int)(m0 + row);
            int li = ((gt >> 10) * 4 + (kt >> 1)) * 1024 + (gt & 1023);
            float linv = 1.f / (L0[li] + L1[li]);
            unsigned int a0[4] = {u0.x, u0.y, u0.z, u0.w};
            unsigned int a1[4] = {u1.x, u1.y, u1.z, u1.w};
            unsigned int w[4];
#pragma unroll
            for (int j = 0; j < 4; ++j) {
                float lo = (bf2f((unsigned short)(a0[j] & 0xffff)) +
                            bf2f((unsigned short)(a1[j] & 0xffff))) * linv;
                float hi = (bf2f((unsigned short)(a0[j] >> 16)) +
                            bf2f((unsigned short)(a1[j] >> 16))) * linv;
                w[j] = f2bf(lo) | ((unsigned int)f2bf(hi) << 16);
            }
            *(uint4*)&As[row][c4 * 8] = make_uint4(w[0], w[1], w[2], w[3]);
        }
#pragma unroll
        for (int j = 0; j < 4; ++j) {
            int lin = j * 256 + tid; int n = lin >> 2, c = lin & 3;
            *(uint4*)&Bs[n][c * 8] =
                *(const uint4*)(Wb + (size_t)n * En + kt * 32 + c * 8);
        }
        __syncthreads();
        bf16x8 af[4], bfr[4];
#pragma unroll
        for (int mt = 0; mt < 4; ++mt)
            af[mt] = *(const bf16x8*)&As[mt * 16 + cl][quad * 8];
#pragma unroll
        for (int nt = 0; nt < 4; ++nt)
            bfr[nt] = *(const bf16x8*)&Bs[wv * 64 + nt * 16 + cl][quad * 8];
#pragma unroll
        for (int mt = 0; mt < 4; ++mt)
#pragma unroll
            for (int nt = 0; nt < 4; ++nt)
                acc[mt][nt] = __builtin_amdgcn_mfma_f32_16x16x32_bf16(af[mt], bfr[nt], acc[mt][nt], 0, 0, 0);
    }
    float bv[4];
#pragma unroll
    for (int nt = 0; nt < 4; ++nt) bv[nt] = bias[wv * 64 + nt * 16 + cl];
    __syncthreads();                               // As/Bs done; Ah phase begins
#pragma unroll
    for (int mt = 0; mt < 4; ++mt)
#pragma unroll
        for (int nt = 0; nt < 4; ++nt)
#pragma unroll
            for (int r = 0; r < 4; ++r) {
                float a = acc[mt][nt][r] + bv[nt];
                unsigned short ab = f2bf(a);
                AOb[(m0 + mt * 16 + quad * 4 + r) * En + wv * 64 + nt * 16 + cl] = ab;
                Ah[mt * 16 + quad * 4 + r][wv * 64 + nt * 16 + cl] = ab;
            }
    __syncthreads();
    // boundary MLP: h1 = Ah @ w1^T (2 MFMAs: hi + lo), relu, *w2, sigmoid
    {
        f32x4 hacc[2] = {{0.f, 0.f, 0.f, 0.f}, {0.f, 0.f, 0.f, 0.f}};
        for (int kt = 0; kt < 8; ++kt) {
            bf16x8 ah = *(const bf16x8*)&Ah[wv * 16 + cl][kt * 32 + quad * 8];
#pragma unroll
            for (int nt = 0; nt < 2; ++nt) {
                size_t off = (size_t)(nt * 16 + cl) * En + kt * 32 + quad * 8;
                bf16x8 bh_ = *(const bf16x8*)(w1h + off);
                bf16x8 bl_ = *(const bf16x8*)(w1l + off);
                hacc[nt] = __builtin_amdgcn_mfma_f32_16x16x32_bf16(ah, bh_, hacc[nt], 0, 0, 0);
                hacc[nt] = __builtin_amdgcn_mfma_f32_16x16x32_bf16(ah, bl_, hacc[nt], 0, 0, 0);
            }
        }
        float b1v[2] = {b1[cl], b1[16 + cl]};
        float w2v[2] = {w2[cl], w2[16 + cl]};
        float b2v = b2[0];
        f32x4 z;
#pragma unroll
        for (int r = 0; r < 4; ++r)
            z[r] = fmaxf(hacc[0][r] + b1v[0], 0.f) * w2v[0] +
                   fmaxf(hacc[1][r] + b1v[1], 0.f) * w2v[1];
#pragma unroll
        for (int d = 1; d < 16; d <<= 1)
#pragma unroll
            for (int r = 0; r < 4; ++r) z[r] += __shfl_xor(z[r], d);
        if (cl == 0) {
#pragma unroll
            for (int r = 0; r < 4; ++r)
                bsc[m0 + wv * 16 + quad * 4 + r] =
                    1.f / (1.f + __expf(-(z[r] + b2v)));
        }
    }
}

// ---------- K4: pool with fused in-block scan; AO read as bf16 ----------
__global__ __launch_bounds__(256) void k_pool(const float* __restrict__ bsc,
                                              const unsigned short* __restrict__ AOb,
                                              float* __restrict__ PE) {
    __shared__ float pre[1024];
    __shared__ float wsl[4];
    __shared__ float stot_s;
    __shared__ int   segs[33];
    int b = blockIdx.y, p = blockIdx.x, t = threadIdx.x;
    int lane = t & 63, wv = t >> 6;
    float4 v = *(const float4*)(bsc + b * 1024 + t * 4);
    float s0 = v.x, s1 = s0 + v.y, s2 = s1 + v.z, s3 = s2 + v.w;
    float ts = s3, sc = ts;
#pragma unroll
    for (int d = 1; d < 64; d <<= 1) {
        float y = __shfl_up(sc, d);
        if (lane >= d) sc += y;
    }
    if (lane == 63) wsl[wv] = sc;
    __syncthreads();
    if (t == 0) {
        float s = 0.f;
        for (int i = 0; i < 4; ++i) { float tmp = wsl[i]; wsl[i] = s; s += tmp; }
        stot_s = s;
    }
    __syncthreads();
    float base = wsl[wv] + (sc - ts);
    pre[t * 4 + 0] = base + s0;
    pre[t * 4 + 1] = base + s1;
    pre[t * 4 + 2] = base + s2;
    pre[t * 4 + 3] = base + s3;
    __syncthreads();
    float denom = stot_s + 1e-6f;
    int lastpid = 0;
#pragma unroll
    for (int i = 0; i < 4; ++i) {
        int t4 = t * 4 + i;
        int pid = min((int)floorf(pre[t4] / denom * 32.0f), 31);
        int pidprev = (t4 == 0) ? -1
                      : min((int)floorf(pre[t4 - 1] / denom * 32.0f), 31);
        for (int pp = pidprev + 1; pp <= pid; ++pp) segs[pp] = t4;
        lastpid = pid;
    }
    if (t == 255)
        for (int pp = lastpid + 1; pp <= 32; ++pp) segs[pp] = Tn;
    __syncthreads();
    int s = segs[p], e = segs[p + 1];
    float sum = 0.f;
    for (int tk = s; tk < e; ++tk)
        sum += bf2f(AOb[((size_t)b * Tn + tk) * En + t]);
    PE[(size_t)(b * Pn + p) * En + t] = sum / fmaxf((float)(e - s), 1.f);
}

// ---------- K5: out = PE @ prw^T + prb  (hi/lo MFMA; 32 blocks now) --------
__global__ __launch_bounds__(256) void k_final(const float* __restrict__ PE,
                                               const unsigned short* __restrict__ pwh,
                                               const unsigned short* __restrict__ pwl,
                                               const float* __restrict__ prb,
                                               float* __restrict__ out) {
    __shared__ unsigned short Ahs[32][40];
    __shared__ unsigned short Als[32][40];
    int tid = threadIdx.x;
    int wv = tid >> 6, lane = tid & 63;
    int cl = lane & 15, quad = lane >> 4;
    int m0 = blockIdx.x * 32;

    f32x4 acc[2][4];
#pragma unroll
    for (int mt = 0; mt < 2; ++mt)
#pragma unroll
        for (int nt = 0; nt < 4; ++nt) acc[mt][nt] = {0.f, 0.f, 0.f, 0.f};

    for (int kt = 0; kt < 8; ++kt) {
        if (kt) __syncthreads();
        {
            int row = tid >> 3, c4 = tid & 7;      // 32 rows × 8 thr
            const float* src = PE + (size_t)(m0 + row) * En + kt * 32 + c4 * 4;
            float4 a = *(const float4*)src;
            float v[4] = {a.x, a.y, a.z, a.w};
            unsigned int hw[2], lw[2];
#pragma unroll
            for (int j = 0; j < 2; ++j) {
                unsigned short h0 = f2bf(v[2 * j]), h1 = f2bf(v[2 * j + 1]);
                unsigned short q0 = f2bf(v[2 * j] - bf2f(h0));
                unsigned short q1 = f2bf(v[2 * j + 1] - bf2f(h1));
                hw[j] = h0 | ((unsigned int)h1 << 16);
                lw[j] = q0 | ((unsigned int)q1 << 16);
            }
            *(uint2*)&Ahs[row][c4 * 4] = make_uint2(hw[0], hw[1]);
            *(uint2*)&Als[row][c4 * 4] = make_uint2(lw[0], lw[1]);
        }
        __syncthreads();
        bf16x8 ah[2], al[2], bh_[4], bl_[4];
#pragma unroll
        for (int mt = 0; mt < 2; ++mt) {
            ah[mt] = *(const bf16x8*)&Ahs[mt * 16 + cl][quad * 8];
            al[mt] = *(const bf16x8*)&Als[mt * 16 + cl][quad * 8];
        }
#pragma unroll
        for (int nt = 0; nt < 4; ++nt) {
            size_t off = (size_t)(wv * 64 + nt * 16 + cl) * En + kt * 32 + quad * 8;
            bh_[nt] = *(const bf16x8*)(pwh + off);
            bl_[nt] = *(const bf16x8*)(pwl + off);
        }
#pragma unroll
        for (int mt = 0; mt < 2; ++mt)
#pragma unroll
            for (int nt = 0; nt < 4; ++nt) {
                acc[mt][nt] = __builtin_amdgcn_mfma_f32_16x16x32_bf16(ah[mt], bh_[nt], acc[mt][nt], 0, 0, 0);
                acc[mt][nt] = __builtin_amdgcn_mfma_f32_16x16x32_bf16(ah[mt], bl_[nt], acc[mt][nt], 0, 0, 0);
                acc[mt][nt] = __builtin_amdgcn_mfma_f32_16x16x32_bf16(al[mt], bh_[nt], acc[mt][nt], 0, 0, 0);
            }
    }
    float bv[4];
#pragma unroll
    for (int nt = 0; nt < 4; ++nt) bv[nt] = prb[wv * 64 + nt * 16 + cl];
#pragma unroll
    for (int mt = 0; mt < 2; ++mt)
#pragma unroll
        for (int nt = 0; nt < 4; ++nt)
#pragma unroll
            for (int r = 0; r < 4; ++r)
                out[(size_t)(m0 + mt * 16 + quad * 4 + r) * En + wv * 64 + nt * 16 + cl] =
                    acc[mt][nt][r] + bv[nt];
}

extern "C" void kernel_launch(void* const* d_in, const int* in_sizes, int n_in,
                              void* d_out, int out_size, void* d_ws, size_t ws_size,
                              hipStream_t stream) {
    const float* x    = (const float*)d_in[0];
    const float* ipw  = (const float*)d_in[1];
    const float* ipb  = (const float*)d_in[2];
    const float* inw  = (const float*)d_in[3];
    const float* inb  = (const float*)d_in[4];
    const float* outw = (const float*)d_in[5];
    const float* outb = (const float*)d_in[6];
    const float* bw1  = (const float*)d_in[7];
    const float* bb1  = (const float*)d_in[8];
    const float* bw2  = (const float*)d_in[9];
    const float* bb2  = (const float*)d_in[10];
    const float* prw  = (const float*)d_in[11];
    const float* prb  = (const float*)d_in[12];

    char* base = (char*)d_ws;
    unsigned short* Qb  = (unsigned short*)base;
    unsigned short* Kb  = Qb + (size_t)8388608;
    unsigned short* AOb = (unsigned short*)base;                        // over Qb (dead after attn)
    unsigned short* Vt  = (unsigned short*)(base + (size_t)33554432);
    float*          PE  = (float*)(base + (size_t)33554432);            // over Vt after attn
    unsigned short* Po0 = (unsigned short*)(base + (size_t)50331648);
    unsigned short* Po1 = (unsigned short*)(base + (size_t)67108864);
    unsigned short* Wcb = (unsigned short*)(base + (size_t)83886080);   // 48 KB
    float*          bc  = (float*)(base + (size_t)83935232);            // 3 KB
    unsigned short* Wb  = (unsigned short*)(base + (size_t)83938304);   // 128 KB
    unsigned short* w1h = (unsigned short*)(base + (size_t)84069376);   // 16 KB
    unsigned short* w1l = (unsigned short*)(base + (size_t)84085760);   // 16 KB
    float*          L0  = (float*)(base + (size_t)84102144);            // 512 KB
    float*          L1  = (float*)(base + (size_t)84626432);            // 512 KB
    float*          bsc = (float*)(base + (size_t)85150720);            // 128 KB
    unsigned short* pwh = (unsigned short*)(base + (size_t)85286912);   // 128 KB
    unsigned short* pwl = (unsigned short*)(base + (size_t)85417984);   // 128 KB

    k_prep<<<288, 256, 0, stream>>>(ipw, ipb, inw, inb, Wcb, bc);
    k_qkv<<<864, 256, 0, stream>>>(x, Wcb, bc, outw, bw1, prw,
                                   Qb, Kb, Vt, Wb, w1h, w1l, pwh, pwl);
    k_attn<<<2048, 256, 0, stream>>>(Qb, Kb, Vt, Po0, Po1, L0, L1);
    k_out<<<512, 256, 0, stream>>>(Po0, Po1, L0, L1, Wb, outb,
                                   w1h, w1l, bb1, bw2, bb2, AOb, bsc);
    k_pool<<<dim3(32, 32), 256, 0, stream>>>(bsc, AOb, PE);
    k_final<<<32, 256, 0, stream>>>(PE, pwh, pwl, prb, (float*)d_out);
}